// Round 1
// 1998.179 us; speedup vs baseline: 1.0012x; 1.0012x over previous
//
#include <hip/hip_runtime.h>
#include <cstdint>
#include <math.h>

// ---------------- problem constants ----------------
static constexpr int NB  = 8;
static constexpr int CC_ = 256;          // channels
static constexpr int HH  = 100, WW = 100, HW = 10000;
static constexpr int KA  = 9;
static constexpr int AN  = HW * KA;      // 90000 anchors/image
static constexpr int PRE  = 3000;
static constexpr int POST = 300;
static constexpr int NW64 = 47;          // ceil(3000/64)
static constexpr float NMS_T = 0.7f;

typedef float v2f __attribute__((ext_vector_type(2)));

__device__ __forceinline__ v2f fma2(v2f a, v2f b, v2f c) {
#if __has_builtin(__builtin_elementwise_fma)
  return __builtin_elementwise_fma(a, b, c);
#else
  v2f r; r[0] = fmaf(a[0], b[0], c[0]); r[1] = fmaf(a[1], b[1], c[1]); return r;
#endif
}

// d_out layout (float offsets)
static constexpr size_t OUT_CLS  = 0;            // 8*2*90000 = 1,440,000
static constexpr size_t OUT_REG  = 1440000;      // 8*90000*4 = 2,880,000
static constexpr size_t OUT_ROIS = 4320000;      // 2400*4
static constexpr size_t OUT_RIND = 4329600;      // 2400
static constexpr size_t OUT_ANCH = 4332000;      // 90000*4

// workspace layout (byte offsets, all 16B-aligned)
static constexpr size_t WS_H     = 0;                          // 81,920,000
static constexpr size_t WS_WT    = 81920000;                   //  2,359,296
static constexpr size_t WS_W54   = WS_WT   + 2359296;          //     55,296
static constexpr size_t WS_BOXES = WS_W54  + 55296;            // 11,520,000
static constexpr size_t WS_KEYS  = WS_BOXES+ 11520000;         //  2,880,000
static constexpr size_t WS_SBOX  = WS_KEYS + 2880000;          //    384,000
static constexpr size_t WS_SVAL  = WS_SBOX + 384000;           //     96,000
static constexpr size_t WS_MASK  = WS_SVAL + 96000;            //  9,048,064

// anchor heights/widths per k = r_idx*3 + s_idx  (fp32 of f64-exact values)
__device__ __constant__ float AHC[9] = {
  90.50966799187809f, 181.01933598375618f, 362.03867196751236f,
  128.f, 256.f, 512.f,
  181.01933598375618f, 362.03867196751236f, 724.0773439350247f };
__device__ __constant__ float AWC[9] = {
  181.01933598375618f, 362.03867196751236f, 724.0773439350247f,
  128.f, 256.f, 512.f,
  90.50966799187809f, 181.01933598375618f, 362.03867196751236f };

// ---------------- prep (single kernel): w1 transpose + head weights + anchors ----------------
__global__ void k_prep_all(const float* __restrict__ w1, const float* __restrict__ wc,
                           const float* __restrict__ wr, float* __restrict__ wT2,
                           float* __restrict__ w54, float* __restrict__ anch) {
  int t = blockIdx.x * 256 + threadIdx.x;
  if (t < 2 * 256 * 9 * 128) {
    int cotile = t / 294912;
    int rem = t % 294912;
    int ci = rem / 1152;
    int r2 = rem % 1152;
    int kk = r2 / 128;
    int col = r2 % 128;
    int co = cotile * 128 + col;
    wT2[t] = w1[(size_t)co * 2304 + ci * 9 + kk];
  }
  if (t < 256 * 54) {
    int ci = t / 54, j = t % 54;
    w54[t] = (j < 18) ? wc[j * 256 + ci] : wr[(j - 18) * 256 + ci];
  }
  int u = t - 256 * 54;
  if (u >= 0 && u < AN) {
    int k = u % KA; int pp = u / KA; int y = pp / WW; int x = pp % WW;
    int ri = k / 3, si = k % 3;
    double scale = (double)(8 << si);
    double r = (ri == 0) ? 0.5 : ((ri == 1) ? 1.0 : 2.0);
    double hh = 16.0 * scale * sqrt(r);
    double ww = 16.0 * scale * sqrt(1.0 / r);
    double sy = y * 16.0, sx = x * 16.0;
    anch[(size_t)u * 4 + 0] = (float)(sy + 8.0 - hh * 0.5);
    anch[(size_t)u * 4 + 1] = (float)(sx + 8.0 - ww * 0.5);
    anch[(size_t)u * 4 + 2] = (float)(sy + 8.0 + hh * 0.5);
    anch[(size_t)u * 4 + 3] = (float)(sx + 8.0 + ww * 0.5);
  }
}

// ---------------- conv 3x3 pad 1 + bias + relu ----------------
// R9: async weight staging. Weights double-buffered in LDS and fetched with
// __builtin_amdgcn_global_load_lds(16B) issued at the START of the compute
// phase for ch+1 -> the compiler's vmcnt(0) drain before the post-compute
// barrier is free (loads had ~4600 cy of FMA to land). x-halo (boundary-
// predicated, can't use glds) is prefetched into 3 VGPRs during compute and
// ds_write'n after the barrier (T14 issue-early/write-late).
// FMA chain per accumulator UNCHANGED (ci asc, ky, kx), pk-paired co — bit-exact
// vs R7/R8, so selection/NMS outputs are identical.
// __launch_bounds__(256,4): VGPR cap 128 (uses ~84, no spill); LDS 39.9KB -> 4 blocks/CU.
// DO NOT use (256,6): 512/6=85 VGPR cap spills accumulators (R6: 14x slower).
typedef __attribute__((address_space(3))) float lds_f;
typedef const __attribute__((address_space(1))) float glb_f;

__global__ __launch_bounds__(256, 4) void k_conv3x3(const float* __restrict__ x,
    const float* __restrict__ wT2, const float* __restrict__ b1,
    float* __restrict__ hout) {
  __shared__ float sx[4][10][18];
  __shared__ float sw[2][4608];
  const int tid = threadIdx.x;
  const int xt = blockIdx.x % 7, yt = blockIdx.x / 7;
  const int cotile = blockIdx.y;
  const int n = blockIdx.z;
  const int x0 = xt * 16, y0 = yt * 8;
  const int tx = tid & 15, g = tid >> 4;

  int slot[3];
  #pragma unroll
  for (int k = 0; k < 3; ++k) {
    int e = tid + 256 * k;
    int c = e / 180; int rem = e - c * 180;
    int row = rem / 18; int col = rem - row * 18;
    int gy = y0 - 1 + row, gx = x0 - 1 + col;
    bool st = (e < 720);
    bool ok = st && gy >= 0 && gy < HH && gx < WW;
    ok = ok && gx >= 0;
    int goff = ok ? (c * HW + gy * WW + gx) : 0;
    int lds = st ? (c * 180 + row * 18 + col) : 0;
    slot[k] = goff | (lds << 17) | (ok ? (1 << 28) : 0) | (st ? (1 << 29) : 0);
  }

  v2f acc2[4][8];
  #pragma unroll
  for (int a = 0; a < 4; ++a)
    #pragma unroll
    for (int b = 0; b < 8; ++b) { acc2[a][b][0] = 0.f; acc2[a][b][1] = 0.f; }

  const float* xn = x + (size_t)n * CC_ * HW;
  const float* wbase = wT2 + (size_t)cotile * (256 * 9 * 128);

  // async stage of one ch-group's weights (4 ci x 9 taps x 128 co = 4608 floats)
  // into sw[buf]; LDS dest is wave-uniform base + lane*16 (e = tid + 256k).
  auto stage_w = [&](int buf, int ch2) {
    const float* wsrc = wbase + (size_t)(ch2 * 4) * 1152;
    #pragma unroll
    for (int k = 0; k < 5; ++k) {
      int e = tid + 256 * k;
      if (e < 1152) {
        __builtin_amdgcn_global_load_lds((glb_f*)(wsrc + (size_t)e * 4),
                                         (lds_f*)(&sw[buf][e * 4]), 16, 0, 0);
      }
    }
  };

  // ---- prologue: stage x(ch=0) directly + issue weights(ch=0) async ----
  #pragma unroll
  for (int k = 0; k < 3; ++k) {
    if (slot[k] & (1 << 29)) {
      float v = 0.f;
      if (slot[k] & (1 << 28)) v = xn[slot[k] & 0x1FFFF];
      ((float*)sx)[(slot[k] >> 17) & 0x7FF] = v;
    }
  }
  stage_w(0, 0);
  __syncthreads();   // drains vmcnt (glds) + lgkm (x writes)

  for (int ch = 0; ch < 64; ++ch) {
    const bool more = (ch + 1 < 64);
    // issue next x-halo into registers + next weights into LDS buf^1,
    // BEFORE compute so the latency hides under ~4600 cy of FMAs
    float xp0 = 0.f, xp1 = 0.f, xp2 = 0.f;
    if (more) {
      const size_t cb = (size_t)(ch + 1) * 4 * HW;
      if (slot[0] & (1 << 28)) xp0 = xn[cb + (slot[0] & 0x1FFFF)];
      if (slot[1] & (1 << 28)) xp1 = xn[cb + (slot[1] & 0x1FFFF)];
      if (slot[2] & (1 << 28)) xp2 = xn[cb + (slot[2] & 0x1FFFF)];
      stage_w((ch + 1) & 1, ch + 1);
    }

    const float* swb = sw[ch & 1];
    for (int c = 0; c < 4; ++c) {
      const float* sxc = &sx[c][0][tx];
      const float* swc = swb + c * 1152 + g * 8;
      float xr[10][3];
      #pragma unroll
      for (int r = 0; r < 10; ++r) {
        #pragma unroll
        for (int kx = 0; kx < 3; ++kx) xr[r][kx] = sxc[r * 18 + kx];
      }
      #pragma unroll
      for (int ky = 0; ky < 3; ++ky) {
        #pragma unroll
        for (int kx = 0; kx < 3; ++kx) {
          const v2f* swv = (const v2f*)(swc + (ky * 3 + kx) * 128);
          const v2f w0 = swv[0], w1 = swv[1], w2 = swv[2], w3 = swv[3];
          #pragma unroll
          for (int yy = 0; yy < 8; ++yy) {
            float xv = xr[yy + ky][kx];
            v2f xv2; xv2[0] = xv; xv2[1] = xv;
            acc2[0][yy] = fma2(w0, xv2, acc2[0][yy]);
            acc2[1][yy] = fma2(w1, xv2, acc2[1][yy]);
            acc2[2][yy] = fma2(w2, xv2, acc2[2][yy]);
            acc2[3][yy] = fma2(w3, xv2, acc2[3][yy]);
          }
        }
      }
    }
    __syncthreads();   // compute done; also guarantees w(ch+1) glds landed
    if (more) {
      if (slot[0] & (1 << 29)) ((float*)sx)[(slot[0] >> 17) & 0x7FF] = xp0;
      if (slot[1] & (1 << 29)) ((float*)sx)[(slot[1] >> 17) & 0x7FF] = xp1;
      if (slot[2] & (1 << 29)) ((float*)sx)[(slot[2] >> 17) & 0x7FF] = xp2;
      __syncthreads(); // x(ch+1) visible
    }
  }

  const int gx = x0 + tx;
  if (gx < WW) {
    #pragma unroll
    for (int p = 0; p < 4; ++p) {
      #pragma unroll
      for (int cm = 0; cm < 2; ++cm) {
        int co = cotile * 128 + g * 8 + 2 * p + cm;
        float bias = b1[co];
        #pragma unroll
        for (int yy = 0; yy < 8; ++yy) {
          int gy = y0 + yy;
          if (gy < HH) {
            float v = acc2[p][yy][cm] + bias;
            hout[((size_t)(n * CC_ + co) * HH + gy) * WW + gx] = fmaxf(v, 0.f);
          }
        }
      }
    }
  }
}

// ---------------- 1x1 heads + decode + score keys (R1/R3 version, proven) ----------------
__global__ __launch_bounds__(256) void k_heads(const float* __restrict__ hin,
    const float* __restrict__ w54, const float* __restrict__ bc, const float* __restrict__ br,
    const int* __restrict__ imw, const int* __restrict__ imh,
    float* __restrict__ cls_out, float* __restrict__ reg_out,
    float* __restrict__ boxes, unsigned int* __restrict__ keys) {
  int gid = blockIdx.x * 256 + threadIdx.x;
  if (gid >= NB * HW) return;
  int n = gid / HW, p = gid % HW;
  float cacc[18], racc[36];
  #pragma unroll
  for (int j = 0; j < 18; ++j) cacc[j] = 0.f;
  #pragma unroll
  for (int j = 0; j < 36; ++j) racc[j] = 0.f;
  const float* hp = hin + (size_t)n * CC_ * HW + p;
  #pragma unroll 2
  for (int ci = 0; ci < CC_; ++ci) {
    float hv = hp[(size_t)ci * HW];
    const float* wrow = w54 + ci * 54;
    #pragma unroll
    for (int j = 0; j < 18; ++j) cacc[j] = fmaf(hv, wrow[j], cacc[j]);
    #pragma unroll
    for (int j = 0; j < 36; ++j) racc[j] = fmaf(hv, wrow[18 + j], racc[j]);
  }
  const float imgW = (float)imw[0], imgH = (float)imh[0];
  const int y = p / WW, xq = p % WW;
  #pragma unroll
  for (int k = 0; k < 9; ++k) {
    float c0 = cacc[2 * k] + bc[2 * k];
    float c1 = cacc[2 * k + 1] + bc[2 * k + 1];
    int a = p * 9 + k;
    cls_out[(size_t)n * 2 * AN + a]      = c0;
    cls_out[(size_t)n * 2 * AN + AN + a] = c1;
    float t0 = racc[4 * k]     + br[4 * k];
    float t1 = racc[4 * k + 1] + br[4 * k + 1];
    float t2 = racc[4 * k + 2] + br[4 * k + 2];
    float t3 = racc[4 * k + 3] + br[4 * k + 3];
    size_t ro = ((size_t)n * AN + a) * 4;
    reg_out[ro] = t0; reg_out[ro + 1] = t1; reg_out[ro + 2] = t2; reg_out[ro + 3] = t3;
    float hk = AHC[k], wk = AWC[k];
    float cy = fmaf(t0, hk, y  * 16.f + 8.f);
    float cx = fmaf(t1, wk, xq * 16.f + 8.f);
    float bh = expf(t2) * hk, bw = expf(t3) * wk;
    float y1 = cy - 0.5f * bh, x1 = cx - 0.5f * bw;
    float y2 = cy + 0.5f * bh, x2 = cx + 0.5f * bw;
    y1 = fminf(fmaxf(y1, 0.f), imgH); y2 = fminf(fmaxf(y2, 0.f), imgH);
    x1 = fminf(fmaxf(x1, 0.f), imgW); x2 = fminf(fmaxf(x2, 0.f), imgW);
    bool valid = (y2 - y1 >= 16.f) && (x2 - x1 >= 16.f);
    boxes[ro] = y1; boxes[ro + 1] = x1; boxes[ro + 2] = y2; boxes[ro + 3] = x2;
    float dc = c1 - c0;                       // monotone in softmax fg
    unsigned u = __float_as_uint(dc);
    u = (u & 0x80000000u) ? ~u : (u | 0x80000000u);
    keys[(size_t)n * AN + a] = valid ? u : 0u;
  }
}

// ---------------- per-image stable top-3000 selection (monolithic, proven R3/R7) ----------------
__global__ __launch_bounds__(1024) void k_select(const unsigned* __restrict__ keys,
    const float* __restrict__ boxes, float* __restrict__ sbox, int* __restrict__ sval) {
  __shared__ unsigned hist[4][1024];
  __shared__ unsigned long long cand[4096];
  __shared__ int sB1, sA1, sB2, scnt;
  const int t = threadIdx.x;
  const int n = blockIdx.x;
  const unsigned* kp = keys + (size_t)n * AN;
  for (int i = t; i < 4096; i += 1024) ((unsigned*)hist)[i] = 0;
  __syncthreads();
  const int rep = (t >> 6) & 3;
  for (int i = t; i < AN; i += 1024) atomicAdd(&hist[rep][kp[i] >> 22], 1u);
  __syncthreads();
  unsigned myc = hist[0][t] + hist[1][t] + hist[2][t] + hist[3][t];
  __syncthreads();
  hist[0][t] = myc;
  __syncthreads();
  for (int off = 1; off < 1024; off <<= 1) {
    unsigned add = (t + off < 1024) ? hist[0][t + off] : 0;
    __syncthreads();
    hist[0][t] += add;
    __syncthreads();
  }
  unsigned incl = hist[0][t];
  unsigned above = incl - myc;
  if (above < (unsigned)PRE && incl >= (unsigned)PRE && myc > 0) { sB1 = t; sA1 = (int)above; }
  __syncthreads();
  const int B1 = sB1, A1 = sA1;
  __syncthreads();
  hist[0][t] = 0;
  __syncthreads();
  for (int i = t; i < AN; i += 1024) {
    unsigned k32 = kp[i];
    if ((int)(k32 >> 22) == B1) atomicAdd(&hist[0][(k32 >> 12) & 1023u], 1u);
  }
  __syncthreads();
  myc = hist[0][t];
  __syncthreads();
  for (int off = 1; off < 1024; off <<= 1) {
    unsigned add = (t + off < 1024) ? hist[0][t + off] : 0;
    __syncthreads();
    hist[0][t] += add;
    __syncthreads();
  }
  incl = hist[0][t]; above = incl - myc;
  const int target = PRE - A1;
  if ((int)above < target && (int)incl >= target && myc > 0) sB2 = t;
  if (t == 0) scnt = 0;
  __syncthreads();
  const int B2 = sB2;
  for (int i = t; i < AN; i += 1024) {
    unsigned k32 = kp[i];
    int b1 = (int)(k32 >> 22);
    bool sel = (b1 > B1) || (b1 == B1 && (int)((k32 >> 12) & 1023u) >= B2);
    if (sel) {
      int pos = atomicAdd(&scnt, 1);
      if (pos < 4096)
        cand[pos] = ((unsigned long long)k32 << 32) | (unsigned long long)(0xFFFFFFFFu - (unsigned)i);
    }
  }
  __syncthreads();
  int cnt = scnt; if (cnt > 4096) cnt = 4096;
  for (int i = cnt + t; i < 4096; i += 1024) cand[i] = 0ull;
  __syncthreads();
  // bitonic sort descending: key = (score_mapped, ~idx)  => score desc, idx asc
  for (int k = 2; k <= 4096; k <<= 1) {
    for (int j = k >> 1; j > 0; j >>= 1) {
      for (int i = t; i < 4096; i += 1024) {
        int ixj = i ^ j;
        if (ixj > i) {
          unsigned long long va = cand[i], vb = cand[ixj];
          bool desc = ((i & k) == 0);
          if (desc ? (va < vb) : (va > vb)) { cand[i] = vb; cand[ixj] = va; }
        }
      }
      __syncthreads();
    }
  }
  for (int i = t; i < PRE; i += 1024) {
    unsigned long long kv = cand[i];
    unsigned idx = 0xFFFFFFFFu - (unsigned)(kv & 0xFFFFFFFFull);
    float4 bb = *(const float4*)(boxes + ((size_t)n * AN + idx) * 4);
    *(float4*)(sbox + ((size_t)n * PRE + i) * 4) = bb;
    sval[n * PRE + i] = ((kv >> 32) != 0ull) ? 1 : 0;
  }
}

// ---------------- NMS suppression bitmask: 4 i-tiles per 256-thread block ----------------
__global__ __launch_bounds__(256) void k_mask(const float* __restrict__ sbox,
    unsigned long long* __restrict__ mask) {
  __shared__ float4 jb[64];
  const int t = threadIdx.x;
  const int lane = t & 63, wv = t >> 6;
  const int jt = blockIdx.x, n = blockIdx.z;
  const int it = blockIdx.y * 4 + wv;
  const int j0 = jt * 64;
  if (t < 64) {
    int jg = j0 + t;
    float4 v = make_float4(0.f, 0.f, 0.f, 0.f);
    if (jg < PRE) v = *(const float4*)(sbox + ((size_t)n * PRE + jg) * 4);
    jb[t] = v;
  }
  __syncthreads();
  const int i = it * 64 + lane;
  if (it >= NW64 || i >= PRE) return;
  float4 bi = *(const float4*)(sbox + ((size_t)n * PRE + i) * 4);
  float areaI = (bi.z - bi.x) * (bi.w - bi.y);
  unsigned long long bits = 0ull;
  #pragma unroll 4
  for (int jj = 0; jj < 64; ++jj) {
    int j = j0 + jj;
    float4 bj = jb[jj];
    float yy1 = fmaxf(bi.x, bj.x), xx1 = fmaxf(bi.y, bj.y);
    float yy2 = fminf(bi.z, bj.z), xx2 = fminf(bi.w, bj.w);
    float inter = fmaxf(yy2 - yy1, 0.f) * fmaxf(xx2 - xx1, 0.f);
    float areaJ = (bj.z - bj.x) * (bj.w - bj.y);
    float iou = inter / (areaI + areaJ - inter + 1e-9f);
    if (iou > NMS_T && j > i && j < PRE) bits |= (1ull << jj);
  }
  mask[((size_t)n * 3008 + i) * NW64 + jt] = bits;
}

// ---------------- fused: sequential greedy NMS scan + rank-compact top-300 ----------------
__global__ __launch_bounds__(256) void k_nms_final(const unsigned long long* __restrict__ mask,
    const int* __restrict__ sval, const float* __restrict__ sbox,
    float* __restrict__ rois, float* __restrict__ rind) {
  __shared__ unsigned long long kws[NW64];
  __shared__ int pref[NW64 + 1];
  const int t = threadIdx.x, n = blockIdx.x;
  // phase 1: wave 0 does the serial greedy scan (identical semantics to k_nms_seq)
  if (t < 64) {
    unsigned long long keep = 0ull;
    for (int w = 0; w < NW64; ++w) {
      int i = w * 64 + t;
      int v = (i < PRE) ? sval[n * PRE + i] : 0;
      unsigned long long m = __ballot(v != 0);
      if (t == w) keep = m;     // in-register, no LDS round-trip needed (single wave)
    }
    const unsigned long long* mrow = mask + (size_t)n * 3008 * NW64;
    unsigned long long buf[16];
    #pragma unroll
    for (int r = 0; r < 16; ++r)
      buf[r] = (t < NW64) ? mrow[(size_t)r * NW64 + t] : 0ull;
    for (int base = 0; base < PRE; base += 16) {
      #pragma unroll
      for (int r = 0; r < 16; ++r) {
        int i = base + r;
        if (i < PRE) {
          unsigned long long kb = __shfl(keep, i >> 6);
          if ((kb >> (i & 63)) & 1ull) keep &= ~buf[r];
        }
        int nx = i + 16;
        buf[r] = (nx < PRE && t < NW64) ? mrow[(size_t)nx * NW64 + t] : 0ull;
      }
    }
    if (t < NW64) kws[t] = keep;
  }
  __syncthreads();
  // phase 2: all threads — identical to k_final
  if (t == 0) {
    int s = 0;
    for (int w = 0; w < NW64; ++w) { pref[w] = s; s += __popcll(kws[w]); }
    pref[NW64] = s;
  }
  for (int e = t; e < POST * 4; e += 256) rois[(size_t)n * POST * 4 + e] = 0.f;
  for (int e = t; e < POST; e += 256) rind[(size_t)n * POST + e] = (float)n;
  __syncthreads();
  for (int i = t; i < PRE; i += 256) {
    int wd = i >> 6, b = i & 63;
    unsigned long long wv = kws[wd];
    if ((wv >> b) & 1ull) {
      int rank = pref[wd] + __popcll(wv & ((1ull << b) - 1ull));
      if (rank < POST) {
        float4 bb = *(const float4*)(sbox + ((size_t)n * PRE + i) * 4);
        *(float4*)(rois + ((size_t)n * POST + rank) * 4) = bb;
      }
    }
  }
}

// ---------------- launch (6 kernels total) ----------------
extern "C" void kernel_launch(void* const* d_in, const int* in_sizes, int n_in,
                              void* d_out, int out_size, void* d_ws, size_t ws_size,
                              hipStream_t stream) {
  const float* x  = (const float*)d_in[0];
  const float* w1 = (const float*)d_in[1];
  const float* b1 = (const float*)d_in[2];
  const float* wc = (const float*)d_in[3];
  const float* bc = (const float*)d_in[4];
  const float* wr = (const float*)d_in[5];
  const float* br = (const float*)d_in[6];
  const int* imw  = (const int*)d_in[7];
  const int* imh  = (const int*)d_in[8];
  float* out = (float*)d_out;
  char* ws = (char*)d_ws;
  float* hbuf = (float*)(ws + WS_H);
  float* wT2  = (float*)(ws + WS_WT);
  float* w54  = (float*)(ws + WS_W54);
  float* boxes = (float*)(ws + WS_BOXES);
  unsigned* keys = (unsigned*)(ws + WS_KEYS);
  float* sbox = (float*)(ws + WS_SBOX);
  int* sval   = (int*)(ws + WS_SVAL);
  unsigned long long* mask  = (unsigned long long*)(ws + WS_MASK);

  k_prep_all<<<2304, 256, 0, stream>>>(w1, wc, wr, wT2, w54, out + OUT_ANCH);
  k_conv3x3<<<dim3(91, 2, NB), 256, 0, stream>>>(x, wT2, b1, hbuf);
  k_heads<<<313, 256, 0, stream>>>(hbuf, w54, bc, br, imw, imh,
                                   out + OUT_CLS, out + OUT_REG, boxes, keys);
  k_select<<<NB, 1024, 0, stream>>>(keys, boxes, sbox, sval);
  k_mask<<<dim3(NW64, 12, NB), 256, 0, stream>>>(sbox, mask);
  k_nms_final<<<NB, 256, 0, stream>>>(mask, sval, sbox, out + OUT_ROIS, out + OUT_RIND);
}

// Round 2
// 1983.488 us; speedup vs baseline: 1.0086x; 1.0074x over previous
//
#include <hip/hip_runtime.h>
#include <cstdint>
#include <math.h>

// ---------------- problem constants ----------------
static constexpr int NB  = 8;
static constexpr int CC_ = 256;          // channels
static constexpr int HH  = 100, WW = 100, HW = 10000;
static constexpr int KA  = 9;
static constexpr int AN  = HW * KA;      // 90000 anchors/image
static constexpr int PRE  = 3000;
static constexpr int POST = 300;
static constexpr int NW64 = 47;          // ceil(3000/64)
static constexpr float NMS_T = 0.7f;

typedef float v2f __attribute__((ext_vector_type(2)));

__device__ __forceinline__ v2f fma2(v2f a, v2f b, v2f c) {
#if __has_builtin(__builtin_elementwise_fma)
  return __builtin_elementwise_fma(a, b, c);
#else
  v2f r; r[0] = fmaf(a[0], b[0], c[0]); r[1] = fmaf(a[1], b[1], c[1]); return r;
#endif
}

// d_out layout (float offsets)
static constexpr size_t OUT_CLS  = 0;            // 8*2*90000 = 1,440,000
static constexpr size_t OUT_REG  = 1440000;      // 8*90000*4 = 2,880,000
static constexpr size_t OUT_ROIS = 4320000;      // 2400*4
static constexpr size_t OUT_RIND = 4329600;      // 2400
static constexpr size_t OUT_ANCH = 4332000;      // 90000*4

// workspace layout (byte offsets, all 16B-aligned)
static constexpr size_t WS_H     = 0;                          // 81,920,000
static constexpr size_t WS_WT    = 81920000;                   //  2,359,296
static constexpr size_t WS_W54   = WS_WT   + 2359296;          //     55,296
static constexpr size_t WS_BOXES = WS_W54  + 55296;            // 11,520,000
static constexpr size_t WS_KEYS  = WS_BOXES+ 11520000;         //  2,880,000
static constexpr size_t WS_SBOX  = WS_KEYS + 2880000;          //    384,000
static constexpr size_t WS_SVAL  = WS_SBOX + 384000;           //     96,000
static constexpr size_t WS_MASK  = WS_SVAL + 96000;            //  9,048,064

// anchor heights/widths per k = r_idx*3 + s_idx  (fp32 of f64-exact values)
__device__ __constant__ float AHC[9] = {
  90.50966799187809f, 181.01933598375618f, 362.03867196751236f,
  128.f, 256.f, 512.f,
  181.01933598375618f, 362.03867196751236f, 724.0773439350247f };
__device__ __constant__ float AWC[9] = {
  181.01933598375618f, 362.03867196751236f, 724.0773439350247f,
  128.f, 256.f, 512.f,
  90.50966799187809f, 181.01933598375618f, 362.03867196751236f };

// ---------------- prep (single kernel): w1 transpose + head weights + anchors ----------------
__global__ void k_prep_all(const float* __restrict__ w1, const float* __restrict__ wc,
                           const float* __restrict__ wr, float* __restrict__ wT2,
                           float* __restrict__ w54, float* __restrict__ anch) {
  int t = blockIdx.x * 256 + threadIdx.x;
  if (t < 2 * 256 * 9 * 128) {
    int cotile = t / 294912;
    int rem = t % 294912;
    int ci = rem / 1152;
    int r2 = rem % 1152;
    int kk = r2 / 128;
    int col = r2 % 128;
    int co = cotile * 128 + col;
    wT2[t] = w1[(size_t)co * 2304 + ci * 9 + kk];
  }
  if (t < 256 * 54) {
    int ci = t / 54, j = t % 54;
    w54[t] = (j < 18) ? wc[j * 256 + ci] : wr[(j - 18) * 256 + ci];
  }
  int u = t - 256 * 54;
  if (u >= 0 && u < AN) {
    int k = u % KA; int pp = u / KA; int y = pp / WW; int x = pp % WW;
    int ri = k / 3, si = k % 3;
    double scale = (double)(8 << si);
    double r = (ri == 0) ? 0.5 : ((ri == 1) ? 1.0 : 2.0);
    double hh = 16.0 * scale * sqrt(r);
    double ww = 16.0 * scale * sqrt(1.0 / r);
    double sy = y * 16.0, sx = x * 16.0;
    anch[(size_t)u * 4 + 0] = (float)(sy + 8.0 - hh * 0.5);
    anch[(size_t)u * 4 + 1] = (float)(sx + 8.0 - ww * 0.5);
    anch[(size_t)u * 4 + 2] = (float)(sy + 8.0 + hh * 0.5);
    anch[(size_t)u * 4 + 3] = (float)(sx + 8.0 + ww * 0.5);
  }
}

// ---------------- conv 3x3 pad 1 + bias + relu ----------------
// R10: single barrier per ch-iteration. sx double-buffered (2x720 floats) so the
// next channel-group's x-halo is ds_written into sx[b^1] BEFORE the one barrier,
// overlapping the FMA phase; weights stay glds-double-buffered in sw[2].
// __launch_bounds__(256,3): VGPR cap 170 (R9's (256,4) squeezed to 64 VGPR = acc
// size alone -> no scheduling headroom). LDS 42.6KB -> 3 blocks/CU either way.
// FMA chain per accumulator UNCHANGED (ci asc, ky, kx), pk-paired co — bit-exact
// vs R7/R8/R9, so selection/NMS outputs are identical.
typedef __attribute__((address_space(3))) float lds_f;
typedef const __attribute__((address_space(1))) float glb_f;

__global__ __launch_bounds__(256, 3) void k_conv3x3(const float* __restrict__ x,
    const float* __restrict__ wT2, const float* __restrict__ b1,
    float* __restrict__ hout) {
  __shared__ float sx[2][720];     // [buf][c*180 + row*18 + col]
  __shared__ float sw[2][4608];
  const int tid = threadIdx.x;
  const int xt = blockIdx.x % 7, yt = blockIdx.x / 7;
  const int cotile = blockIdx.y;
  const int n = blockIdx.z;
  const int x0 = xt * 16, y0 = yt * 8;
  const int tx = tid & 15, g = tid >> 4;

  int slot[3];
  #pragma unroll
  for (int k = 0; k < 3; ++k) {
    int e = tid + 256 * k;
    int c = e / 180; int rem = e - c * 180;
    int row = rem / 18; int col = rem - row * 18;
    int gy = y0 - 1 + row, gx = x0 - 1 + col;
    bool st = (e < 720);
    bool ok = st && gy >= 0 && gy < HH && gx < WW;
    ok = ok && gx >= 0;
    int goff = ok ? (c * HW + gy * WW + gx) : 0;
    int lds = st ? (c * 180 + row * 18 + col) : 0;
    slot[k] = goff | (lds << 17) | (ok ? (1 << 28) : 0) | (st ? (1 << 29) : 0);
  }

  v2f acc2[4][8];
  #pragma unroll
  for (int a = 0; a < 4; ++a)
    #pragma unroll
    for (int b = 0; b < 8; ++b) { acc2[a][b][0] = 0.f; acc2[a][b][1] = 0.f; }

  const float* xn = x + (size_t)n * CC_ * HW;
  const float* wbase = wT2 + (size_t)cotile * (256 * 9 * 128);

  // async stage of one ch-group's weights (4 ci x 9 taps x 128 co = 4608 floats)
  // into sw[buf]; LDS dest is wave-uniform base + lane*16 (e = tid + 256k).
  auto stage_w = [&](int buf, int ch2) {
    const float* wsrc = wbase + (size_t)(ch2 * 4) * 1152;
    #pragma unroll
    for (int k = 0; k < 5; ++k) {
      int e = tid + 256 * k;
      if (e < 1152) {
        __builtin_amdgcn_global_load_lds((glb_f*)(wsrc + (size_t)e * 4),
                                         (lds_f*)(&sw[buf][e * 4]), 16, 0, 0);
      }
    }
  };

  // ---- prologue: stage x(ch=0) directly + issue weights(ch=0) async ----
  #pragma unroll
  for (int k = 0; k < 3; ++k) {
    if (slot[k] & (1 << 29)) {
      float v = 0.f;
      if (slot[k] & (1 << 28)) v = xn[slot[k] & 0x1FFFF];
      sx[0][(slot[k] >> 17) & 0x7FF] = v;
    }
  }
  stage_w(0, 0);
  __syncthreads();   // drains vmcnt (glds) + lgkm (x writes)

  for (int ch = 0; ch < 64; ++ch) {
    const int b = ch & 1;
    const bool more = (ch + 1 < 64);
    // issue next x-halo into registers + next weights into LDS buf^1,
    // BEFORE compute so the latency hides under ~4600 cy of FMAs
    float xp0 = 0.f, xp1 = 0.f, xp2 = 0.f;
    if (more) {
      const size_t cb = (size_t)(ch + 1) * 4 * HW;
      if (slot[0] & (1 << 28)) xp0 = xn[cb + (slot[0] & 0x1FFFF)];
      if (slot[1] & (1 << 28)) xp1 = xn[cb + (slot[1] & 0x1FFFF)];
      if (slot[2] & (1 << 28)) xp2 = xn[cb + (slot[2] & 0x1FFFF)];
      stage_w(b ^ 1, ch + 1);
    }

    const float* swb = sw[b];
    const float* sxb = sx[b];
    for (int c = 0; c < 4; ++c) {
      const float* sxc = sxb + c * 180 + tx;
      const float* swc = swb + c * 1152 + g * 8;
      float xr[10][3];
      #pragma unroll
      for (int r = 0; r < 10; ++r) {
        #pragma unroll
        for (int kx = 0; kx < 3; ++kx) xr[r][kx] = sxc[r * 18 + kx];
      }
      #pragma unroll
      for (int ky = 0; ky < 3; ++ky) {
        #pragma unroll
        for (int kx = 0; kx < 3; ++kx) {
          const v2f* swv = (const v2f*)(swc + (ky * 3 + kx) * 128);
          const v2f w0 = swv[0], w1 = swv[1], w2 = swv[2], w3 = swv[3];
          #pragma unroll
          for (int yy = 0; yy < 8; ++yy) {
            float xv = xr[yy + ky][kx];
            v2f xv2; xv2[0] = xv; xv2[1] = xv;
            acc2[0][yy] = fma2(w0, xv2, acc2[0][yy]);
            acc2[1][yy] = fma2(w1, xv2, acc2[1][yy]);
            acc2[2][yy] = fma2(w2, xv2, acc2[2][yy]);
            acc2[3][yy] = fma2(w3, xv2, acc2[3][yy]);
          }
        }
      }
    }
    // publish x(ch+1) into the OTHER sx buffer (nobody reads it during ch),
    // then ONE barrier makes both sx[b^1] and sw[b^1] (glds) visible.
    if (more) {
      if (slot[0] & (1 << 29)) sx[b ^ 1][(slot[0] >> 17) & 0x7FF] = xp0;
      if (slot[1] & (1 << 29)) sx[b ^ 1][(slot[1] >> 17) & 0x7FF] = xp1;
      if (slot[2] & (1 << 29)) sx[b ^ 1][(slot[2] >> 17) & 0x7FF] = xp2;
    }
    __syncthreads();
  }

  const int gx = x0 + tx;
  if (gx < WW) {
    #pragma unroll
    for (int p = 0; p < 4; ++p) {
      #pragma unroll
      for (int cm = 0; cm < 2; ++cm) {
        int co = cotile * 128 + g * 8 + 2 * p + cm;
        float bias = b1[co];
        #pragma unroll
        for (int yy = 0; yy < 8; ++yy) {
          int gy = y0 + yy;
          if (gy < HH) {
            float v = acc2[p][yy][cm] + bias;
            hout[((size_t)(n * CC_ + co) * HH + gy) * WW + gx] = fmaxf(v, 0.f);
          }
        }
      }
    }
  }
}

// ---------------- 1x1 heads + decode + score keys ----------------
// R10: ci-loop unroll 2->8. Only ~1.2 blocks/CU of TLP exist (313 blocks), so the
// strided hbuf reads need ~8-deep ILP to cover ~900cy HBM latency (108cy FMA/iter).
// FMA order per accumulator unchanged (ci ascending) — bit-exact.
__global__ __launch_bounds__(256) void k_heads(const float* __restrict__ hin,
    const float* __restrict__ w54, const float* __restrict__ bc, const float* __restrict__ br,
    const int* __restrict__ imw, const int* __restrict__ imh,
    float* __restrict__ cls_out, float* __restrict__ reg_out,
    float* __restrict__ boxes, unsigned int* __restrict__ keys) {
  int gid = blockIdx.x * 256 + threadIdx.x;
  if (gid >= NB * HW) return;
  int n = gid / HW, p = gid % HW;
  float cacc[18], racc[36];
  #pragma unroll
  for (int j = 0; j < 18; ++j) cacc[j] = 0.f;
  #pragma unroll
  for (int j = 0; j < 36; ++j) racc[j] = 0.f;
  const float* hp = hin + (size_t)n * CC_ * HW + p;
  #pragma unroll 8
  for (int ci = 0; ci < CC_; ++ci) {
    float hv = hp[(size_t)ci * HW];
    const float* wrow = w54 + ci * 54;
    #pragma unroll
    for (int j = 0; j < 18; ++j) cacc[j] = fmaf(hv, wrow[j], cacc[j]);
    #pragma unroll
    for (int j = 0; j < 36; ++j) racc[j] = fmaf(hv, wrow[18 + j], racc[j]);
  }
  const float imgW = (float)imw[0], imgH = (float)imh[0];
  const int y = p / WW, xq = p % WW;
  #pragma unroll
  for (int k = 0; k < 9; ++k) {
    float c0 = cacc[2 * k] + bc[2 * k];
    float c1 = cacc[2 * k + 1] + bc[2 * k + 1];
    int a = p * 9 + k;
    cls_out[(size_t)n * 2 * AN + a]      = c0;
    cls_out[(size_t)n * 2 * AN + AN + a] = c1;
    float t0 = racc[4 * k]     + br[4 * k];
    float t1 = racc[4 * k + 1] + br[4 * k + 1];
    float t2 = racc[4 * k + 2] + br[4 * k + 2];
    float t3 = racc[4 * k + 3] + br[4 * k + 3];
    size_t ro = ((size_t)n * AN + a) * 4;
    reg_out[ro] = t0; reg_out[ro + 1] = t1; reg_out[ro + 2] = t2; reg_out[ro + 3] = t3;
    float hk = AHC[k], wk = AWC[k];
    float cy = fmaf(t0, hk, y  * 16.f + 8.f);
    float cx = fmaf(t1, wk, xq * 16.f + 8.f);
    float bh = expf(t2) * hk, bw = expf(t3) * wk;
    float y1 = cy - 0.5f * bh, x1 = cx - 0.5f * bw;
    float y2 = cy + 0.5f * bh, x2 = cx + 0.5f * bw;
    y1 = fminf(fmaxf(y1, 0.f), imgH); y2 = fminf(fmaxf(y2, 0.f), imgH);
    x1 = fminf(fmaxf(x1, 0.f), imgW); x2 = fminf(fmaxf(x2, 0.f), imgW);
    bool valid = (y2 - y1 >= 16.f) && (x2 - x1 >= 16.f);
    boxes[ro] = y1; boxes[ro + 1] = x1; boxes[ro + 2] = y2; boxes[ro + 3] = x2;
    float dc = c1 - c0;                       // monotone in softmax fg
    unsigned u = __float_as_uint(dc);
    u = (u & 0x80000000u) ? ~u : (u | 0x80000000u);
    keys[(size_t)n * AN + a] = valid ? u : 0u;
  }
}

// ---------------- per-image stable top-3000 selection (monolithic, proven R3/R7) ----------------
__global__ __launch_bounds__(1024) void k_select(const unsigned* __restrict__ keys,
    const float* __restrict__ boxes, float* __restrict__ sbox, int* __restrict__ sval) {
  __shared__ unsigned hist[4][1024];
  __shared__ unsigned long long cand[4096];
  __shared__ int sB1, sA1, sB2, scnt;
  const int t = threadIdx.x;
  const int n = blockIdx.x;
  const unsigned* kp = keys + (size_t)n * AN;
  for (int i = t; i < 4096; i += 1024) ((unsigned*)hist)[i] = 0;
  __syncthreads();
  const int rep = (t >> 6) & 3;
  for (int i = t; i < AN; i += 1024) atomicAdd(&hist[rep][kp[i] >> 22], 1u);
  __syncthreads();
  unsigned myc = hist[0][t] + hist[1][t] + hist[2][t] + hist[3][t];
  __syncthreads();
  hist[0][t] = myc;
  __syncthreads();
  for (int off = 1; off < 1024; off <<= 1) {
    unsigned add = (t + off < 1024) ? hist[0][t + off] : 0;
    __syncthreads();
    hist[0][t] += add;
    __syncthreads();
  }
  unsigned incl = hist[0][t];
  unsigned above = incl - myc;
  if (above < (unsigned)PRE && incl >= (unsigned)PRE && myc > 0) { sB1 = t; sA1 = (int)above; }
  __syncthreads();
  const int B1 = sB1, A1 = sA1;
  __syncthreads();
  hist[0][t] = 0;
  __syncthreads();
  for (int i = t; i < AN; i += 1024) {
    unsigned k32 = kp[i];
    if ((int)(k32 >> 22) == B1) atomicAdd(&hist[0][(k32 >> 12) & 1023u], 1u);
  }
  __syncthreads();
  myc = hist[0][t];
  __syncthreads();
  for (int off = 1; off < 1024; off <<= 1) {
    unsigned add = (t + off < 1024) ? hist[0][t + off] : 0;
    __syncthreads();
    hist[0][t] += add;
    __syncthreads();
  }
  incl = hist[0][t]; above = incl - myc;
  const int target = PRE - A1;
  if ((int)above < target && (int)incl >= target && myc > 0) sB2 = t;
  if (t == 0) scnt = 0;
  __syncthreads();
  const int B2 = sB2;
  for (int i = t; i < AN; i += 1024) {
    unsigned k32 = kp[i];
    int b1 = (int)(k32 >> 22);
    bool sel = (b1 > B1) || (b1 == B1 && (int)((k32 >> 12) & 1023u) >= B2);
    if (sel) {
      int pos = atomicAdd(&scnt, 1);
      if (pos < 4096)
        cand[pos] = ((unsigned long long)k32 << 32) | (unsigned long long)(0xFFFFFFFFu - (unsigned)i);
    }
  }
  __syncthreads();
  int cnt = scnt; if (cnt > 4096) cnt = 4096;
  for (int i = cnt + t; i < 4096; i += 1024) cand[i] = 0ull;
  __syncthreads();
  // bitonic sort descending: key = (score_mapped, ~idx)  => score desc, idx asc
  for (int k = 2; k <= 4096; k <<= 1) {
    for (int j = k >> 1; j > 0; j >>= 1) {
      for (int i = t; i < 4096; i += 1024) {
        int ixj = i ^ j;
        if (ixj > i) {
          unsigned long long va = cand[i], vb = cand[ixj];
          bool desc = ((i & k) == 0);
          if (desc ? (va < vb) : (va > vb)) { cand[i] = vb; cand[ixj] = va; }
        }
      }
      __syncthreads();
    }
  }
  for (int i = t; i < PRE; i += 1024) {
    unsigned long long kv = cand[i];
    unsigned idx = 0xFFFFFFFFu - (unsigned)(kv & 0xFFFFFFFFull);
    float4 bb = *(const float4*)(boxes + ((size_t)n * AN + idx) * 4);
    *(float4*)(sbox + ((size_t)n * PRE + i) * 4) = bb;
    sval[n * PRE + i] = ((kv >> 32) != 0ull) ? 1 : 0;
  }
}

// ---------------- NMS suppression bitmask: 4 i-tiles per 256-thread block ----------------
__global__ __launch_bounds__(256) void k_mask(const float* __restrict__ sbox,
    unsigned long long* __restrict__ mask) {
  __shared__ float4 jb[64];
  const int t = threadIdx.x;
  const int lane = t & 63, wv = t >> 6;
  const int jt = blockIdx.x, n = blockIdx.z;
  const int it = blockIdx.y * 4 + wv;
  const int j0 = jt * 64;
  if (t < 64) {
    int jg = j0 + t;
    float4 v = make_float4(0.f, 0.f, 0.f, 0.f);
    if (jg < PRE) v = *(const float4*)(sbox + ((size_t)n * PRE + jg) * 4);
    jb[t] = v;
  }
  __syncthreads();
  const int i = it * 64 + lane;
  if (it >= NW64 || i >= PRE) return;
  float4 bi = *(const float4*)(sbox + ((size_t)n * PRE + i) * 4);
  float areaI = (bi.z - bi.x) * (bi.w - bi.y);
  unsigned long long bits = 0ull;
  #pragma unroll 4
  for (int jj = 0; jj < 64; ++jj) {
    int j = j0 + jj;
    float4 bj = jb[jj];
    float yy1 = fmaxf(bi.x, bj.x), xx1 = fmaxf(bi.y, bj.y);
    float yy2 = fminf(bi.z, bj.z), xx2 = fminf(bi.w, bj.w);
    float inter = fmaxf(yy2 - yy1, 0.f) * fmaxf(xx2 - xx1, 0.f);
    float areaJ = (bj.z - bj.x) * (bj.w - bj.y);
    float iou = inter / (areaI + areaJ - inter + 1e-9f);
    if (iou > NMS_T && j > i && j < PRE) bits |= (1ull << jj);
  }
  mask[((size_t)n * 3008 + i) * NW64 + jt] = bits;
}

// ---------------- fused: sequential greedy NMS scan + rank-compact top-300 ----------------
__global__ __launch_bounds__(256) void k_nms_final(const unsigned long long* __restrict__ mask,
    const int* __restrict__ sval, const float* __restrict__ sbox,
    float* __restrict__ rois, float* __restrict__ rind) {
  __shared__ unsigned long long kws[NW64];
  __shared__ int pref[NW64 + 1];
  const int t = threadIdx.x, n = blockIdx.x;
  // phase 1: wave 0 does the serial greedy scan (identical semantics to k_nms_seq)
  if (t < 64) {
    unsigned long long keep = 0ull;
    for (int w = 0; w < NW64; ++w) {
      int i = w * 64 + t;
      int v = (i < PRE) ? sval[n * PRE + i] : 0;
      unsigned long long m = __ballot(v != 0);
      if (t == w) keep = m;     // in-register, no LDS round-trip needed (single wave)
    }
    const unsigned long long* mrow = mask + (size_t)n * 3008 * NW64;
    unsigned long long buf[16];
    #pragma unroll
    for (int r = 0; r < 16; ++r)
      buf[r] = (t < NW64) ? mrow[(size_t)r * NW64 + t] : 0ull;
    for (int base = 0; base < PRE; base += 16) {
      #pragma unroll
      for (int r = 0; r < 16; ++r) {
        int i = base + r;
        if (i < PRE) {
          unsigned long long kb = __shfl(keep, i >> 6);
          if ((kb >> (i & 63)) & 1ull) keep &= ~buf[r];
        }
        int nx = i + 16;
        buf[r] = (nx < PRE && t < NW64) ? mrow[(size_t)nx * NW64 + t] : 0ull;
      }
    }
    if (t < NW64) kws[t] = keep;
  }
  __syncthreads();
  // phase 2: all threads — identical to k_final
  if (t == 0) {
    int s = 0;
    for (int w = 0; w < NW64; ++w) { pref[w] = s; s += __popcll(kws[w]); }
    pref[NW64] = s;
  }
  for (int e = t; e < POST * 4; e += 256) rois[(size_t)n * POST * 4 + e] = 0.f;
  for (int e = t; e < POST; e += 256) rind[(size_t)n * POST + e] = (float)n;
  __syncthreads();
  for (int i = t; i < PRE; i += 256) {
    int wd = i >> 6, b = i & 63;
    unsigned long long wv = kws[wd];
    if ((wv >> b) & 1ull) {
      int rank = pref[wd] + __popcll(wv & ((1ull << b) - 1ull));
      if (rank < POST) {
        float4 bb = *(const float4*)(sbox + ((size_t)n * PRE + i) * 4);
        *(float4*)(rois + ((size_t)n * POST + rank) * 4) = bb;
      }
    }
  }
}

// ---------------- launch (6 kernels total) ----------------
extern "C" void kernel_launch(void* const* d_in, const int* in_sizes, int n_in,
                              void* d_out, int out_size, void* d_ws, size_t ws_size,
                              hipStream_t stream) {
  const float* x  = (const float*)d_in[0];
  const float* w1 = (const float*)d_in[1];
  const float* b1 = (const float*)d_in[2];
  const float* wc = (const float*)d_in[3];
  const float* bc = (const float*)d_in[4];
  const float* wr = (const float*)d_in[5];
  const float* br = (const float*)d_in[6];
  const int* imw  = (const int*)d_in[7];
  const int* imh  = (const int*)d_in[8];
  float* out = (float*)d_out;
  char* ws = (char*)d_ws;
  float* hbuf = (float*)(ws + WS_H);
  float* wT2  = (float*)(ws + WS_WT);
  float* w54  = (float*)(ws + WS_W54);
  float* boxes = (float*)(ws + WS_BOXES);
  unsigned* keys = (unsigned*)(ws + WS_KEYS);
  float* sbox = (float*)(ws + WS_SBOX);
  int* sval   = (int*)(ws + WS_SVAL);
  unsigned long long* mask  = (unsigned long long*)(ws + WS_MASK);

  k_prep_all<<<2304, 256, 0, stream>>>(w1, wc, wr, wT2, w54, out + OUT_ANCH);
  k_conv3x3<<<dim3(91, 2, NB), 256, 0, stream>>>(x, wT2, b1, hbuf);
  k_heads<<<313, 256, 0, stream>>>(hbuf, w54, bc, br, imw, imh,
                                   out + OUT_CLS, out + OUT_REG, boxes, keys);
  k_select<<<NB, 1024, 0, stream>>>(keys, boxes, sbox, sval);
  k_mask<<<dim3(NW64, 12, NB), 256, 0, stream>>>(sbox, mask);
  k_nms_final<<<NB, 256, 0, stream>>>(mask, sval, sbox, out + OUT_ROIS, out + OUT_RIND);
}

// Round 3
// 1304.729 us; speedup vs baseline: 1.5333x; 1.5202x over previous
//
#include <hip/hip_runtime.h>
#include <cstdint>
#include <math.h>

// ---------------- problem constants ----------------
static constexpr int NB  = 8;
static constexpr int CC_ = 256;          // channels
static constexpr int HH  = 100, WW = 100, HW = 10000;
static constexpr int KA  = 9;
static constexpr int AN  = HW * KA;      // 90000 anchors/image
static constexpr int PRE  = 3000;
static constexpr int POST = 300;
static constexpr int NW64 = 47;          // ceil(3000/64)
static constexpr float NMS_T = 0.7f;

typedef _Float16 f16;
typedef _Float16 f16x8 __attribute__((ext_vector_type(8)));
typedef float f32x4 __attribute__((ext_vector_type(4)));

// d_out layout (float offsets)
static constexpr size_t OUT_CLS  = 0;            // 8*2*90000 = 1,440,000
static constexpr size_t OUT_REG  = 1440000;      // 8*90000*4 = 2,880,000
static constexpr size_t OUT_ROIS = 4320000;      // 2400*4
static constexpr size_t OUT_RIND = 4329600;      // 2400
static constexpr size_t OUT_ANCH = 4332000;      // 90000*4

// workspace layout (byte offsets, all 16B-aligned) — identical to R10.
// WS_WT region (2,359,296 B) now holds WH (1,179,648) + WL (1,179,648):
// split-f16 weights in A-fragment order [tap9][kg8][kq4][co256][8ci].
static constexpr size_t WS_H     = 0;                          // 81,920,000
static constexpr size_t WS_WT    = 81920000;                   //  2,359,296
static constexpr size_t WS_W54   = WS_WT   + 2359296;          //     55,296
static constexpr size_t WS_BOXES = WS_W54  + 55296;            // 11,520,000
static constexpr size_t WS_KEYS  = WS_BOXES+ 11520000;         //  2,880,000
static constexpr size_t WS_SBOX  = WS_KEYS + 2880000;          //    384,000
static constexpr size_t WS_SVAL  = WS_SBOX + 384000;           //     96,000
static constexpr size_t WS_MASK  = WS_SVAL + 96000;            //  9,048,064

// anchor heights/widths per k = r_idx*3 + s_idx  (fp32 of f64-exact values)
__device__ __constant__ float AHC[9] = {
  90.50966799187809f, 181.01933598375618f, 362.03867196751236f,
  128.f, 256.f, 512.f,
  181.01933598375618f, 362.03867196751236f, 724.0773439350247f };
__device__ __constant__ float AWC[9] = {
  181.01933598375618f, 362.03867196751236f, 724.0773439350247f,
  128.f, 256.f, 512.f,
  90.50966799187809f, 181.01933598375618f, 362.03867196751236f };

// ---------------- prep: split-f16 weights (A-frag order) + head weights + anchors ----------
__global__ void k_prep_all(const float* __restrict__ w1, const float* __restrict__ wc,
                           const float* __restrict__ wr, f16* __restrict__ WH,
                           f16* __restrict__ WL, float* __restrict__ w54,
                           float* __restrict__ anch) {
  int t = blockIdx.x * 256 + threadIdx.x;
  if (t < 589824) {
    // t = (((tap*8 + kg)*4 + kq)*256 + co)*8 + cil ; ci = kg*32 + kq*8 + cil
    int cil = t & 7, co = (t >> 3) & 255, rr = t >> 11;
    int kq = rr & 3, kg = (rr >> 2) & 7, tap = rr >> 5;
    int ci = kg * 32 + kq * 8 + cil;
    float v = w1[((size_t)co * 256 + ci) * 9 + tap];
    f16 hi = (f16)v;
    float res = v - (float)hi;
    WH[t] = hi;
    WL[t] = (f16)(res * 2048.f);     // scaled-lo: exact pow2 scale, avoids f16 denorm loss
  }
  if (t < 256 * 54) {
    int ci = t / 54, j = t % 54;
    w54[t] = (j < 18) ? wc[j * 256 + ci] : wr[(j - 18) * 256 + ci];
  }
  int u = t - 256 * 54;
  if (u >= 0 && u < AN) {
    int k = u % KA; int pp = u / KA; int y = pp / WW; int x = pp % WW;
    int ri = k / 3, si = k % 3;
    double scale = (double)(8 << si);
    double r = (ri == 0) ? 0.5 : ((ri == 1) ? 1.0 : 2.0);
    double hh = 16.0 * scale * sqrt(r);
    double ww = 16.0 * scale * sqrt(1.0 / r);
    double sy = y * 16.0, sx = x * 16.0;
    anch[(size_t)u * 4 + 0] = (float)(sy + 8.0 - hh * 0.5);
    anch[(size_t)u * 4 + 1] = (float)(sx + 8.0 - ww * 0.5);
    anch[(size_t)u * 4 + 2] = (float)(sy + 8.0 + hh * 0.5);
    anch[(size_t)u * 4 + 3] = (float)(sx + 8.0 + ww * 0.5);
  }
}

// ---------------- conv 3x3 pad 1 + bias + relu — split-f16 MFMA implicit GEMM ----------------
// R11: h = Σ xh*wh + 2^-11 * Σ(xh*wlS + xlS*wh); lo parts pre-scaled 2^11 so f16
// stays normal; products exact in f32 MFMA accumulator; dropped lo*lo ~2^-22 =>
// h error ~1e-6 (same order as fp32 FMA-reorder) => selection chain stable.
// Fragment layouts per verified guide claims (m89/m91/m92): A/B 8-contig-K per
// lane, row/col = lane&15, khalf = lane>>4; C/D col=lane&15, row=(lane>>4)*4+reg.
// Block: 128co x 128px (16x8 pixel tile), 4 waves = 2(co) x 2(y), wave = 4x4 frags.
// x-tile LDS [buf][hl][kq][pix180][8ci], dbuf, conflict-free b128 both directions;
// staging: threads 0..179 own one pixel, 32-ci register prefetch (T14).
__global__ __launch_bounds__(256, 2) void k_conv3x3(const float* __restrict__ x,
    const f16* __restrict__ WH, const f16* __restrict__ WL,
    const float* __restrict__ b1, float* __restrict__ hout) {
  __shared__ __align__(16) f16 SX[2][2][4][180][8];
  const int tid = threadIdx.x;
  const int lane = tid & 63;
  const int w = tid >> 6;
  const int xt = blockIdx.x % 7, yt = blockIdx.x / 7;
  const int cotile = blockIdx.y;
  const int n = blockIdx.z;
  const int x0 = xt * 16, y0 = yt * 8;
  const int wy = (w & 1) * 4;          // wave's y-row offset within 8-row tile
  const int wc = (w >> 1) * 64;        // wave's co offset within 128
  const int xb = lane & 15, kh = lane >> 4;

  // staging constants: threads 0..179 each own one (r,c) of the 10x18 halo tile
  const int sp = tid;
  const bool s_on = sp < 180;
  const int s_r = sp / 18, s_c = sp % 18;
  const int gy = y0 - 1 + s_r, gx = x0 - 1 + s_c;
  const bool s_ok = s_on && gy >= 0 && gy < HH && gx >= 0 && gx < WW;
  const int s_goff = s_ok ? gy * WW + gx : 0;

  const float* xn = x + (size_t)n * CC_ * HW;

  f32x4 acc1[4][4], acc2[4][4];
  #pragma unroll
  for (int a = 0; a < 4; ++a)
    #pragma unroll
    for (int b = 0; b < 4; ++b) {
      acc1[a][b] = (f32x4){0.f, 0.f, 0.f, 0.f};
      acc2[a][b] = (f32x4){0.f, 0.f, 0.f, 0.f};
    }

  float xv[32];
  auto prefetch = [&](int kg2) {
    if (s_ok) {
      const float* bp = xn + (size_t)(kg2 * 32) * HW + s_goff;
      #pragma unroll
      for (int j = 0; j < 32; ++j) xv[j] = bp[(size_t)j * HW];
    } else {
      #pragma unroll
      for (int j = 0; j < 32; ++j) xv[j] = 0.f;
    }
  };
  auto commit = [&](int nb) {
    if (s_on) {
      #pragma unroll
      for (int q = 0; q < 4; ++q) {
        f16x8 H, L;
        #pragma unroll
        for (int j = 0; j < 8; ++j) {
          float v = xv[q * 8 + j];
          f16 hi = (f16)v;
          float res = v - (float)hi;
          H[j] = hi;
          L[j] = (f16)(res * 2048.f);
        }
        *(f16x8*)&SX[nb][0][q][sp][0] = H;
        *(f16x8*)&SX[nb][1][q][sp][0] = L;
      }
    }
  };

  // prologue: stage ci-group 0
  prefetch(0);
  commit(0);
  __syncthreads();

  const int cob = cotile * 128 + wc;
  for (int kg = 0; kg < 8; ++kg) {
    const int buf = kg & 1;
    if (kg < 7) prefetch(kg + 1);   // issue early: hides under 432 MFMAs (T14)
    #pragma unroll
    for (int ky = 0; ky < 3; ++ky) {
      #pragma unroll
      for (int kx = 0; kx < 3; ++kx) {
        const int tap = ky * 3 + kx;
        const size_t wbase = ((((size_t)tap * 8 + kg) * 4 + kh) * 256 + cob + xb) * 8;
        f16x8 ah[4], al[4], bh[4], bl[4];
        #pragma unroll
        for (int cf = 0; cf < 4; ++cf) {
          ah[cf] = *(const f16x8*)(WH + wbase + (size_t)cf * 128);  // +16 co
          al[cf] = *(const f16x8*)(WL + wbase + (size_t)cf * 128);
        }
        #pragma unroll
        for (int nf = 0; nf < 4; ++nf) {
          const int pixf = (wy + nf + ky) * 18 + xb + kx;
          bh[nf] = *(const f16x8*)&SX[buf][0][kh][pixf][0];
          bl[nf] = *(const f16x8*)&SX[buf][1][kh][pixf][0];
        }
        #pragma unroll
        for (int cf = 0; cf < 4; ++cf)
          #pragma unroll
          for (int nf = 0; nf < 4; ++nf) {
            acc1[cf][nf] = __builtin_amdgcn_mfma_f32_16x16x32_f16(ah[cf], bh[nf], acc1[cf][nf], 0, 0, 0);
            acc2[cf][nf] = __builtin_amdgcn_mfma_f32_16x16x32_f16(ah[cf], bl[nf], acc2[cf][nf], 0, 0, 0);
            acc2[cf][nf] = __builtin_amdgcn_mfma_f32_16x16x32_f16(al[cf], bh[nf], acc2[cf][nf], 0, 0, 0);
          }
      }
    }
    if (kg < 7) commit(buf ^ 1);    // write-late into the other buffer
    __syncthreads();
  }

  // epilogue: combine accumulators, bias, relu, store (C/D: col=lane&15=x, row=kh*4+reg=co)
  const int xg = x0 + xb;
  #pragma unroll
  for (int cf = 0; cf < 4; ++cf)
    #pragma unroll
    for (int r = 0; r < 4; ++r) {
      const int co = cob + cf * 16 + kh * 4 + r;
      const float bias = b1[co];
      const size_t obase = (size_t)(n * CC_ + co) * HH;
      #pragma unroll
      for (int nf = 0; nf < 4; ++nf) {
        const int yg = y0 + wy + nf;
        if (yg < HH && xg < WW) {
          float v = fmaf(acc2[cf][nf][r], 0.00048828125f, acc1[cf][nf][r]) + bias;
          hout[(obase + yg) * WW + xg] = fmaxf(v, 0.f);
        }
      }
    }
}

// ---------------- 1x1 heads + decode + score keys ----------------
__global__ __launch_bounds__(256) void k_heads(const float* __restrict__ hin,
    const float* __restrict__ w54, const float* __restrict__ bc, const float* __restrict__ br,
    const int* __restrict__ imw, const int* __restrict__ imh,
    float* __restrict__ cls_out, float* __restrict__ reg_out,
    float* __restrict__ boxes, unsigned int* __restrict__ keys) {
  int gid = blockIdx.x * 256 + threadIdx.x;
  if (gid >= NB * HW) return;
  int n = gid / HW, p = gid % HW;
  float cacc[18], racc[36];
  #pragma unroll
  for (int j = 0; j < 18; ++j) cacc[j] = 0.f;
  #pragma unroll
  for (int j = 0; j < 36; ++j) racc[j] = 0.f;
  const float* hp = hin + (size_t)n * CC_ * HW + p;
  #pragma unroll 8
  for (int ci = 0; ci < CC_; ++ci) {
    float hv = hp[(size_t)ci * HW];
    const float* wrow = w54 + ci * 54;
    #pragma unroll
    for (int j = 0; j < 18; ++j) cacc[j] = fmaf(hv, wrow[j], cacc[j]);
    #pragma unroll
    for (int j = 0; j < 36; ++j) racc[j] = fmaf(hv, wrow[18 + j], racc[j]);
  }
  const float imgW = (float)imw[0], imgH = (float)imh[0];
  const int y = p / WW, xq = p % WW;
  #pragma unroll
  for (int k = 0; k < 9; ++k) {
    float c0 = cacc[2 * k] + bc[2 * k];
    float c1 = cacc[2 * k + 1] + bc[2 * k + 1];
    int a = p * 9 + k;
    cls_out[(size_t)n * 2 * AN + a]      = c0;
    cls_out[(size_t)n * 2 * AN + AN + a] = c1;
    float t0 = racc[4 * k]     + br[4 * k];
    float t1 = racc[4 * k + 1] + br[4 * k + 1];
    float t2 = racc[4 * k + 2] + br[4 * k + 2];
    float t3 = racc[4 * k + 3] + br[4 * k + 3];
    size_t ro = ((size_t)n * AN + a) * 4;
    reg_out[ro] = t0; reg_out[ro + 1] = t1; reg_out[ro + 2] = t2; reg_out[ro + 3] = t3;
    float hk = AHC[k], wk = AWC[k];
    float cy = fmaf(t0, hk, y  * 16.f + 8.f);
    float cx = fmaf(t1, wk, xq * 16.f + 8.f);
    float bh = expf(t2) * hk, bw = expf(t3) * wk;
    float y1 = cy - 0.5f * bh, x1 = cx - 0.5f * bw;
    float y2 = cy + 0.5f * bh, x2 = cx + 0.5f * bw;
    y1 = fminf(fmaxf(y1, 0.f), imgH); y2 = fminf(fmaxf(y2, 0.f), imgH);
    x1 = fminf(fmaxf(x1, 0.f), imgW); x2 = fminf(fmaxf(x2, 0.f), imgW);
    bool valid = (y2 - y1 >= 16.f) && (x2 - x1 >= 16.f);
    boxes[ro] = y1; boxes[ro + 1] = x1; boxes[ro + 2] = y2; boxes[ro + 3] = x2;
    float dc = c1 - c0;                       // monotone in softmax fg
    unsigned u = __float_as_uint(dc);
    u = (u & 0x80000000u) ? ~u : (u | 0x80000000u);
    keys[(size_t)n * AN + a] = valid ? u : 0u;
  }
}

// ---------------- per-image stable top-3000 selection (monolithic, proven R3/R7) ----------------
__global__ __launch_bounds__(1024) void k_select(const unsigned* __restrict__ keys,
    const float* __restrict__ boxes, float* __restrict__ sbox, int* __restrict__ sval) {
  __shared__ unsigned hist[4][1024];
  __shared__ unsigned long long cand[4096];
  __shared__ int sB1, sA1, sB2, scnt;
  const int t = threadIdx.x;
  const int n = blockIdx.x;
  const unsigned* kp = keys + (size_t)n * AN;
  for (int i = t; i < 4096; i += 1024) ((unsigned*)hist)[i] = 0;
  __syncthreads();
  const int rep = (t >> 6) & 3;
  for (int i = t; i < AN; i += 1024) atomicAdd(&hist[rep][kp[i] >> 22], 1u);
  __syncthreads();
  unsigned myc = hist[0][t] + hist[1][t] + hist[2][t] + hist[3][t];
  __syncthreads();
  hist[0][t] = myc;
  __syncthreads();
  for (int off = 1; off < 1024; off <<= 1) {
    unsigned add = (t + off < 1024) ? hist[0][t + off] : 0;
    __syncthreads();
    hist[0][t] += add;
    __syncthreads();
  }
  unsigned incl = hist[0][t];
  unsigned above = incl - myc;
  if (above < (unsigned)PRE && incl >= (unsigned)PRE && myc > 0) { sB1 = t; sA1 = (int)above; }
  __syncthreads();
  const int B1 = sB1, A1 = sA1;
  __syncthreads();
  hist[0][t] = 0;
  __syncthreads();
  for (int i = t; i < AN; i += 1024) {
    unsigned k32 = kp[i];
    if ((int)(k32 >> 22) == B1) atomicAdd(&hist[0][(k32 >> 12) & 1023u], 1u);
  }
  __syncthreads();
  myc = hist[0][t];
  __syncthreads();
  for (int off = 1; off < 1024; off <<= 1) {
    unsigned add = (t + off < 1024) ? hist[0][t + off] : 0;
    __syncthreads();
    hist[0][t] += add;
    __syncthreads();
  }
  incl = hist[0][t]; above = incl - myc;
  const int target = PRE - A1;
  if ((int)above < target && (int)incl >= target && myc > 0) sB2 = t;
  if (t == 0) scnt = 0;
  __syncthreads();
  const int B2 = sB2;
  for (int i = t; i < AN; i += 1024) {
    unsigned k32 = kp[i];
    int b1 = (int)(k32 >> 22);
    bool sel = (b1 > B1) || (b1 == B1 && (int)((k32 >> 12) & 1023u) >= B2);
    if (sel) {
      int pos = atomicAdd(&scnt, 1);
      if (pos < 4096)
        cand[pos] = ((unsigned long long)k32 << 32) | (unsigned long long)(0xFFFFFFFFu - (unsigned)i);
    }
  }
  __syncthreads();
  int cnt = scnt; if (cnt > 4096) cnt = 4096;
  for (int i = cnt + t; i < 4096; i += 1024) cand[i] = 0ull;
  __syncthreads();
  // bitonic sort descending: key = (score_mapped, ~idx)  => score desc, idx asc
  for (int k = 2; k <= 4096; k <<= 1) {
    for (int j = k >> 1; j > 0; j >>= 1) {
      for (int i = t; i < 4096; i += 1024) {
        int ixj = i ^ j;
        if (ixj > i) {
          unsigned long long va = cand[i], vb = cand[ixj];
          bool desc = ((i & k) == 0);
          if (desc ? (va < vb) : (va > vb)) { cand[i] = vb; cand[ixj] = va; }
        }
      }
      __syncthreads();
    }
  }
  for (int i = t; i < PRE; i += 1024) {
    unsigned long long kv = cand[i];
    unsigned idx = 0xFFFFFFFFu - (unsigned)(kv & 0xFFFFFFFFull);
    float4 bb = *(const float4*)(boxes + ((size_t)n * AN + idx) * 4);
    *(float4*)(sbox + ((size_t)n * PRE + i) * 4) = bb;
    sval[n * PRE + i] = ((kv >> 32) != 0ull) ? 1 : 0;
  }
}

// ---------------- NMS suppression bitmask: 4 i-tiles per 256-thread block ----------------
__global__ __launch_bounds__(256) void k_mask(const float* __restrict__ sbox,
    unsigned long long* __restrict__ mask) {
  __shared__ float4 jb[64];
  const int t = threadIdx.x;
  const int lane = t & 63, wv = t >> 6;
  const int jt = blockIdx.x, n = blockIdx.z;
  const int it = blockIdx.y * 4 + wv;
  const int j0 = jt * 64;
  if (t < 64) {
    int jg = j0 + t;
    float4 v = make_float4(0.f, 0.f, 0.f, 0.f);
    if (jg < PRE) v = *(const float4*)(sbox + ((size_t)n * PRE + jg) * 4);
    jb[t] = v;
  }
  __syncthreads();
  const int i = it * 64 + lane;
  if (it >= NW64 || i >= PRE) return;
  float4 bi = *(const float4*)(sbox + ((size_t)n * PRE + i) * 4);
  float areaI = (bi.z - bi.x) * (bi.w - bi.y);
  unsigned long long bits = 0ull;
  #pragma unroll 4
  for (int jj = 0; jj < 64; ++jj) {
    int j = j0 + jj;
    float4 bj = jb[jj];
    float yy1 = fmaxf(bi.x, bj.x), xx1 = fmaxf(bi.y, bj.y);
    float yy2 = fminf(bi.z, bj.z), xx2 = fminf(bi.w, bj.w);
    float inter = fmaxf(yy2 - yy1, 0.f) * fmaxf(xx2 - xx1, 0.f);
    float areaJ = (bj.z - bj.x) * (bj.w - bj.y);
    float iou = inter / (areaI + areaJ - inter + 1e-9f);
    if (iou > NMS_T && j > i && j < PRE) bits |= (1ull << jj);
  }
  mask[((size_t)n * 3008 + i) * NW64 + jt] = bits;
}

// ---------------- fused: sequential greedy NMS scan + rank-compact top-300 ----------------
__global__ __launch_bounds__(256) void k_nms_final(const unsigned long long* __restrict__ mask,
    const int* __restrict__ sval, const float* __restrict__ sbox,
    float* __restrict__ rois, float* __restrict__ rind) {
  __shared__ unsigned long long kws[NW64];
  __shared__ int pref[NW64 + 1];
  const int t = threadIdx.x, n = blockIdx.x;
  // phase 1: wave 0 does the serial greedy scan (identical semantics to k_nms_seq)
  if (t < 64) {
    unsigned long long keep = 0ull;
    for (int w = 0; w < NW64; ++w) {
      int i = w * 64 + t;
      int v = (i < PRE) ? sval[n * PRE + i] : 0;
      unsigned long long m = __ballot(v != 0);
      if (t == w) keep = m;     // in-register, no LDS round-trip needed (single wave)
    }
    const unsigned long long* mrow = mask + (size_t)n * 3008 * NW64;
    unsigned long long buf[16];
    #pragma unroll
    for (int r = 0; r < 16; ++r)
      buf[r] = (t < NW64) ? mrow[(size_t)r * NW64 + t] : 0ull;
    for (int base = 0; base < PRE; base += 16) {
      #pragma unroll
      for (int r = 0; r < 16; ++r) {
        int i = base + r;
        if (i < PRE) {
          unsigned long long kb = __shfl(keep, i >> 6);
          if ((kb >> (i & 63)) & 1ull) keep &= ~buf[r];
        }
        int nx = i + 16;
        buf[r] = (nx < PRE && t < NW64) ? mrow[(size_t)nx * NW64 + t] : 0ull;
      }
    }
    if (t < NW64) kws[t] = keep;
  }
  __syncthreads();
  // phase 2: all threads — identical to k_final
  if (t == 0) {
    int s = 0;
    for (int w = 0; w < NW64; ++w) { pref[w] = s; s += __popcll(kws[w]); }
    pref[NW64] = s;
  }
  for (int e = t; e < POST * 4; e += 256) rois[(size_t)n * POST * 4 + e] = 0.f;
  for (int e = t; e < POST; e += 256) rind[(size_t)n * POST + e] = (float)n;
  __syncthreads();
  for (int i = t; i < PRE; i += 256) {
    int wd = i >> 6, b = i & 63;
    unsigned long long wv = kws[wd];
    if ((wv >> b) & 1ull) {
      int rank = pref[wd] + __popcll(wv & ((1ull << b) - 1ull));
      if (rank < POST) {
        float4 bb = *(const float4*)(sbox + ((size_t)n * PRE + i) * 4);
        *(float4*)(rois + ((size_t)n * POST + rank) * 4) = bb;
      }
    }
  }
}

// ---------------- launch (6 kernels total) ----------------
extern "C" void kernel_launch(void* const* d_in, const int* in_sizes, int n_in,
                              void* d_out, int out_size, void* d_ws, size_t ws_size,
                              hipStream_t stream) {
  const float* x  = (const float*)d_in[0];
  const float* w1 = (const float*)d_in[1];
  const float* b1 = (const float*)d_in[2];
  const float* wc = (const float*)d_in[3];
  const float* bc = (const float*)d_in[4];
  const float* wr = (const float*)d_in[5];
  const float* br = (const float*)d_in[6];
  const int* imw  = (const int*)d_in[7];
  const int* imh  = (const int*)d_in[8];
  float* out = (float*)d_out;
  char* ws = (char*)d_ws;
  float* hbuf = (float*)(ws + WS_H);
  f16* WH     = (f16*)(ws + WS_WT);
  f16* WL     = (f16*)(ws + WS_WT + 1179648);
  float* w54  = (float*)(ws + WS_W54);
  float* boxes = (float*)(ws + WS_BOXES);
  unsigned* keys = (unsigned*)(ws + WS_KEYS);
  float* sbox = (float*)(ws + WS_SBOX);
  int* sval   = (int*)(ws + WS_SVAL);
  unsigned long long* mask  = (unsigned long long*)(ws + WS_MASK);

  k_prep_all<<<2304, 256, 0, stream>>>(w1, wc, wr, WH, WL, w54, out + OUT_ANCH);
  k_conv3x3<<<dim3(91, 2, NB), 256, 0, stream>>>(x, WH, WL, b1, hbuf);
  k_heads<<<313, 256, 0, stream>>>(hbuf, w54, bc, br, imw, imh,
                                   out + OUT_CLS, out + OUT_REG, boxes, keys);
  k_select<<<NB, 1024, 0, stream>>>(keys, boxes, sbox, sval);
  k_mask<<<dim3(NW64, 12, NB), 256, 0, stream>>>(sbox, mask);
  k_nms_final<<<NB, 256, 0, stream>>>(mask, sval, sbox, out + OUT_ROIS, out + OUT_RIND);
}

// Round 4
// 1289.705 us; speedup vs baseline: 1.5512x; 1.0116x over previous
//
#include <hip/hip_runtime.h>
#include <cstdint>
#include <math.h>

// ---------------- problem constants ----------------
static constexpr int NB  = 8;
static constexpr int CC_ = 256;          // channels
static constexpr int HH  = 100, WW = 100, HW = 10000;
static constexpr int KA  = 9;
static constexpr int AN  = HW * KA;      // 90000 anchors/image
static constexpr int PRE  = 3000;
static constexpr int POST = 300;
static constexpr int NW64 = 47;          // ceil(3000/64)
static constexpr float NMS_T = 0.7f;

typedef _Float16 f16;
typedef _Float16 f16x8 __attribute__((ext_vector_type(8)));
typedef float f32x4 __attribute__((ext_vector_type(4)));

// d_out layout (float offsets)
static constexpr size_t OUT_CLS  = 0;            // 8*2*90000 = 1,440,000
static constexpr size_t OUT_REG  = 1440000;      // 8*90000*4 = 2,880,000
static constexpr size_t OUT_ROIS = 4320000;      // 2400*4
static constexpr size_t OUT_RIND = 4329600;      // 2400
static constexpr size_t OUT_ANCH = 4332000;      // 90000*4

// workspace layout (byte offsets, all 16B-aligned)
// WS_WT region holds WH (1,179,648) + WL (1,179,648): split-f16 weights in
// A-fragment order [tap9][kg8][kq4][co256][8ci].
static constexpr size_t WS_H     = 0;                          // 81,920,000
static constexpr size_t WS_WT    = 81920000;                   //  2,359,296
static constexpr size_t WS_W54   = WS_WT   + 2359296;          //     55,296
static constexpr size_t WS_BOXES = WS_W54  + 55296;            // 11,520,000
static constexpr size_t WS_KEYS  = WS_BOXES+ 11520000;         //  2,880,000
static constexpr size_t WS_SBOX  = WS_KEYS + 2880000;          //    384,000
static constexpr size_t WS_SVAL  = WS_SBOX + 384000;           //     96,000
static constexpr size_t WS_MASK  = WS_SVAL + 96000;            //  9,048,064

// anchor heights/widths per k = r_idx*3 + s_idx  (fp32 of f64-exact values)
__device__ __constant__ float AHC[9] = {
  90.50966799187809f, 181.01933598375618f, 362.03867196751236f,
  128.f, 256.f, 512.f,
  181.01933598375618f, 362.03867196751236f, 724.0773439350247f };
__device__ __constant__ float AWC[9] = {
  181.01933598375618f, 362.03867196751236f, 724.0773439350247f,
  128.f, 256.f, 512.f,
  90.50966799187809f, 181.01933598375618f, 362.03867196751236f };

// ---------------- prep: split-f16 weights (A-frag order) + head weights + anchors ----------
__global__ void k_prep_all(const float* __restrict__ w1, const float* __restrict__ wc,
                           const float* __restrict__ wr, f16* __restrict__ WH,
                           f16* __restrict__ WL, float* __restrict__ w54,
                           float* __restrict__ anch) {
  int t = blockIdx.x * 256 + threadIdx.x;
  if (t < 589824) {
    // t = (((tap*8 + kg)*4 + kq)*256 + co)*8 + cil ; ci = kg*32 + kq*8 + cil
    int cil = t & 7, co = (t >> 3) & 255, rr = t >> 11;
    int kq = rr & 3, kg = (rr >> 2) & 7, tap = rr >> 5;
    int ci = kg * 32 + kq * 8 + cil;
    float v = w1[((size_t)co * 256 + ci) * 9 + tap];
    f16 hi = (f16)v;
    float res = v - (float)hi;
    WH[t] = hi;
    WL[t] = (f16)(res * 2048.f);     // scaled-lo: exact pow2 scale, avoids f16 denorm loss
  }
  if (t < 256 * 54) {
    int ci = t / 54, j = t % 54;
    w54[t] = (j < 18) ? wc[j * 256 + ci] : wr[(j - 18) * 256 + ci];
  }
  int u = t - 256 * 54;
  if (u >= 0 && u < AN) {
    int k = u % KA; int pp = u / KA; int y = pp / WW; int x = pp % WW;
    int ri = k / 3, si = k % 3;
    double scale = (double)(8 << si);
    double r = (ri == 0) ? 0.5 : ((ri == 1) ? 1.0 : 2.0);
    double hh = 16.0 * scale * sqrt(r);
    double ww = 16.0 * scale * sqrt(1.0 / r);
    double sy = y * 16.0, sx = x * 16.0;
    anch[(size_t)u * 4 + 0] = (float)(sy + 8.0 - hh * 0.5);
    anch[(size_t)u * 4 + 1] = (float)(sx + 8.0 - ww * 0.5);
    anch[(size_t)u * 4 + 2] = (float)(sy + 8.0 + hh * 0.5);
    anch[(size_t)u * 4 + 3] = (float)(sx + 8.0 + ww * 0.5);
  }
}

// ---------------- conv 3x3 pad 1 + bias + relu — split-f16 MFMA implicit GEMM ----------------
// R12: occupancy fix. R11 was register-bound (acc 128 AGPR + 128 VGPR = 2 waves/SIMD,
// 22.6% occ, MfmaUtil 22.5%). Wave tile 4cfx4nf -> 2cfx4nf: acc 64 regs, A-loads/tap
// 16->4 global; block = 64co x 128px, grid 91x4x8. Staging prefetch split into two
// 16-reg halves (issue-early / write-late, T14). LDS pix dim 180->181: kh-region
// stride 724 dwords = 20 mod 32 banks -> staggers the 4 kh groups (was 16 -> overlap).
// __launch_bounds__(256,3): ~145 est. regs fits 170 cap -> 3 waves/SIMD, 3 blocks/CU.
// MFMA accumulation order UNCHANGED (kg asc, tap asc, 3-term order) — conv output
// bit-exact vs R11 => selection/NMS identical.
__global__ __launch_bounds__(256, 3) void k_conv3x3(const float* __restrict__ x,
    const f16* __restrict__ WH, const f16* __restrict__ WL,
    const float* __restrict__ b1, float* __restrict__ hout) {
  __shared__ __align__(16) f16 SX[2][2][4][181][8];   // [buf][hl][kq][pix(padded)][8ci]
  const int tid = threadIdx.x;
  const int lane = tid & 63;
  const int w = tid >> 6;
  const int xt = blockIdx.x % 7, yt = blockIdx.x / 7;
  const int cotile = blockIdx.y;      // 0..3 : 64 co each
  const int n = blockIdx.z;
  const int x0 = xt * 16, y0 = yt * 8;
  const int wy = (w & 1) * 4;         // wave's 4-row strip within 8-row tile
  const int wc = (w >> 1) * 32;       // wave's 32-co slice within 64
  const int xb = lane & 15, kh = lane >> 4;

  // staging: threads 0..179 each own one (r,c) of the 10x18 halo tile
  const int sp = tid;
  const bool s_on = sp < 180;
  const int s_r = sp / 18, s_c = sp % 18;
  const int gy = y0 - 1 + s_r, gx = x0 - 1 + s_c;
  const bool s_ok = s_on && gy >= 0 && gy < HH && gx >= 0 && gx < WW;
  const int s_goff = s_ok ? gy * WW + gx : 0;

  const float* xn = x + (size_t)n * CC_ * HW;

  f32x4 acc1[2][4], acc2[2][4];
  #pragma unroll
  for (int a = 0; a < 2; ++a)
    #pragma unroll
    for (int b = 0; b < 4; ++b) {
      acc1[a][b] = (f32x4){0.f, 0.f, 0.f, 0.f};
      acc2[a][b] = (f32x4){0.f, 0.f, 0.f, 0.f};
    }

  float xv[16];
  auto prefetch16 = [&](int kg2, int half) {
    if (s_ok) {
      const float* bp = xn + (size_t)(kg2 * 32 + half * 16) * HW + s_goff;
      #pragma unroll
      for (int j = 0; j < 16; ++j) xv[j] = bp[(size_t)j * HW];
    } else {
      #pragma unroll
      for (int j = 0; j < 16; ++j) xv[j] = 0.f;
    }
  };
  auto commit16 = [&](int nb, int half) {
    if (s_on) {
      #pragma unroll
      for (int q = 0; q < 2; ++q) {
        f16x8 H, L;
        #pragma unroll
        for (int j = 0; j < 8; ++j) {
          float v = xv[q * 8 + j];
          f16 hi = (f16)v;
          float res = v - (float)hi;
          H[j] = hi;
          L[j] = (f16)(res * 2048.f);
        }
        *(f16x8*)&SX[nb][0][half * 2 + q][sp][0] = H;
        *(f16x8*)&SX[nb][1][half * 2 + q][sp][0] = L;
      }
    }
  };

  // prologue: stage ci-group 0 (both halves)
  prefetch16(0, 0); commit16(0, 0);
  prefetch16(0, 1); commit16(0, 1);
  __syncthreads();

  const int cob = cotile * 64 + wc;
  for (int kg = 0; kg < 8; ++kg) {
    const int buf = kg & 1;
    const bool more = (kg < 7);
    if (more) prefetch16(kg + 1, 0);   // issue early: hides under ~4 taps of MFMA
    #pragma unroll
    for (int t9 = 0; t9 < 9; ++t9) {
      const int ky = t9 / 3, kx = t9 % 3;
      const size_t wbase = ((((size_t)t9 * 8 + kg) * 4 + kh) * 256 + cob + xb) * 8;
      f16x8 ah[2], al[2], bh[4], bl[4];
      #pragma unroll
      for (int cf = 0; cf < 2; ++cf) {
        ah[cf] = *(const f16x8*)(WH + wbase + (size_t)cf * 128);  // +16 co
        al[cf] = *(const f16x8*)(WL + wbase + (size_t)cf * 128);
      }
      #pragma unroll
      for (int nf = 0; nf < 4; ++nf) {
        const int pixf = (wy + nf + ky) * 18 + xb + kx;
        bh[nf] = *(const f16x8*)&SX[buf][0][kh][pixf][0];
        bl[nf] = *(const f16x8*)&SX[buf][1][kh][pixf][0];
      }
      #pragma unroll
      for (int cf = 0; cf < 2; ++cf)
        #pragma unroll
        for (int nf = 0; nf < 4; ++nf) {
          acc1[cf][nf] = __builtin_amdgcn_mfma_f32_16x16x32_f16(ah[cf], bh[nf], acc1[cf][nf], 0, 0, 0);
          acc2[cf][nf] = __builtin_amdgcn_mfma_f32_16x16x32_f16(ah[cf], bl[nf], acc2[cf][nf], 0, 0, 0);
          acc2[cf][nf] = __builtin_amdgcn_mfma_f32_16x16x32_f16(al[cf], bh[nf], acc2[cf][nf], 0, 0, 0);
        }
      if (t9 == 3 && more) {
        commit16(buf ^ 1, 0);          // write-late into the other buffer
        prefetch16(kg + 1, 1);         // issue 2nd half; hides under taps 4..8
      }
    }
    if (more) commit16(buf ^ 1, 1);
    __syncthreads();
  }

  // epilogue: combine, bias, relu, store (C/D: col=lane&15=x, row=kh*4+reg=co)
  const int xg = x0 + xb;
  #pragma unroll
  for (int cf = 0; cf < 2; ++cf)
    #pragma unroll
    for (int r = 0; r < 4; ++r) {
      const int co = cob + cf * 16 + kh * 4 + r;
      const float bias = b1[co];
      const size_t obase = (size_t)(n * CC_ + co) * HH;
      #pragma unroll
      for (int nf = 0; nf < 4; ++nf) {
        const int yg = y0 + wy + nf;
        if (yg < HH && xg < WW) {
          float v = fmaf(acc2[cf][nf][r], 0.00048828125f, acc1[cf][nf][r]) + bias;
          hout[(obase + yg) * WW + xg] = fmaxf(v, 0.f);
        }
      }
    }
}

// ---------------- 1x1 heads + decode + score keys ----------------
__global__ __launch_bounds__(256) void k_heads(const float* __restrict__ hin,
    const float* __restrict__ w54, const float* __restrict__ bc, const float* __restrict__ br,
    const int* __restrict__ imw, const int* __restrict__ imh,
    float* __restrict__ cls_out, float* __restrict__ reg_out,
    float* __restrict__ boxes, unsigned int* __restrict__ keys) {
  int gid = blockIdx.x * 256 + threadIdx.x;
  if (gid >= NB * HW) return;
  int n = gid / HW, p = gid % HW;
  float cacc[18], racc[36];
  #pragma unroll
  for (int j = 0; j < 18; ++j) cacc[j] = 0.f;
  #pragma unroll
  for (int j = 0; j < 36; ++j) racc[j] = 0.f;
  const float* hp = hin + (size_t)n * CC_ * HW + p;
  #pragma unroll 8
  for (int ci = 0; ci < CC_; ++ci) {
    float hv = hp[(size_t)ci * HW];
    const float* wrow = w54 + ci * 54;
    #pragma unroll
    for (int j = 0; j < 18; ++j) cacc[j] = fmaf(hv, wrow[j], cacc[j]);
    #pragma unroll
    for (int j = 0; j < 36; ++j) racc[j] = fmaf(hv, wrow[18 + j], racc[j]);
  }
  const float imgW = (float)imw[0], imgH = (float)imh[0];
  const int y = p / WW, xq = p % WW;
  #pragma unroll
  for (int k = 0; k < 9; ++k) {
    float c0 = cacc[2 * k] + bc[2 * k];
    float c1 = cacc[2 * k + 1] + bc[2 * k + 1];
    int a = p * 9 + k;
    cls_out[(size_t)n * 2 * AN + a]      = c0;
    cls_out[(size_t)n * 2 * AN + AN + a] = c1;
    float t0 = racc[4 * k]     + br[4 * k];
    float t1 = racc[4 * k + 1] + br[4 * k + 1];
    float t2 = racc[4 * k + 2] + br[4 * k + 2];
    float t3 = racc[4 * k + 3] + br[4 * k + 3];
    size_t ro = ((size_t)n * AN + a) * 4;
    reg_out[ro] = t0; reg_out[ro + 1] = t1; reg_out[ro + 2] = t2; reg_out[ro + 3] = t3;
    float hk = AHC[k], wk = AWC[k];
    float cy = fmaf(t0, hk, y  * 16.f + 8.f);
    float cx = fmaf(t1, wk, xq * 16.f + 8.f);
    float bh = expf(t2) * hk, bw = expf(t3) * wk;
    float y1 = cy - 0.5f * bh, x1 = cx - 0.5f * bw;
    float y2 = cy + 0.5f * bh, x2 = cx + 0.5f * bw;
    y1 = fminf(fmaxf(y1, 0.f), imgH); y2 = fminf(fmaxf(y2, 0.f), imgH);
    x1 = fminf(fmaxf(x1, 0.f), imgW); x2 = fminf(fmaxf(x2, 0.f), imgW);
    bool valid = (y2 - y1 >= 16.f) && (x2 - x1 >= 16.f);
    boxes[ro] = y1; boxes[ro + 1] = x1; boxes[ro + 2] = y2; boxes[ro + 3] = x2;
    float dc = c1 - c0;                       // monotone in softmax fg
    unsigned u = __float_as_uint(dc);
    u = (u & 0x80000000u) ? ~u : (u | 0x80000000u);
    keys[(size_t)n * AN + a] = valid ? u : 0u;
  }
}

// ---------------- per-image stable top-3000 selection (monolithic, proven R3/R7) ----------------
__global__ __launch_bounds__(1024) void k_select(const unsigned* __restrict__ keys,
    const float* __restrict__ boxes, float* __restrict__ sbox, int* __restrict__ sval) {
  __shared__ unsigned hist[4][1024];
  __shared__ unsigned long long cand[4096];
  __shared__ int sB1, sA1, sB2, scnt;
  const int t = threadIdx.x;
  const int n = blockIdx.x;
  const unsigned* kp = keys + (size_t)n * AN;
  for (int i = t; i < 4096; i += 1024) ((unsigned*)hist)[i] = 0;
  __syncthreads();
  const int rep = (t >> 6) & 3;
  for (int i = t; i < AN; i += 1024) atomicAdd(&hist[rep][kp[i] >> 22], 1u);
  __syncthreads();
  unsigned myc = hist[0][t] + hist[1][t] + hist[2][t] + hist[3][t];
  __syncthreads();
  hist[0][t] = myc;
  __syncthreads();
  for (int off = 1; off < 1024; off <<= 1) {
    unsigned add = (t + off < 1024) ? hist[0][t + off] : 0;
    __syncthreads();
    hist[0][t] += add;
    __syncthreads();
  }
  unsigned incl = hist[0][t];
  unsigned above = incl - myc;
  if (above < (unsigned)PRE && incl >= (unsigned)PRE && myc > 0) { sB1 = t; sA1 = (int)above; }
  __syncthreads();
  const int B1 = sB1, A1 = sA1;
  __syncthreads();
  hist[0][t] = 0;
  __syncthreads();
  for (int i = t; i < AN; i += 1024) {
    unsigned k32 = kp[i];
    if ((int)(k32 >> 22) == B1) atomicAdd(&hist[0][(k32 >> 12) & 1023u], 1u);
  }
  __syncthreads();
  myc = hist[0][t];
  __syncthreads();
  for (int off = 1; off < 1024; off <<= 1) {
    unsigned add = (t + off < 1024) ? hist[0][t + off] : 0;
    __syncthreads();
    hist[0][t] += add;
    __syncthreads();
  }
  incl = hist[0][t]; above = incl - myc;
  const int target = PRE - A1;
  if ((int)above < target && (int)incl >= target && myc > 0) sB2 = t;
  if (t == 0) scnt = 0;
  __syncthreads();
  const int B2 = sB2;
  for (int i = t; i < AN; i += 1024) {
    unsigned k32 = kp[i];
    int b1 = (int)(k32 >> 22);
    bool sel = (b1 > B1) || (b1 == B1 && (int)((k32 >> 12) & 1023u) >= B2);
    if (sel) {
      int pos = atomicAdd(&scnt, 1);
      if (pos < 4096)
        cand[pos] = ((unsigned long long)k32 << 32) | (unsigned long long)(0xFFFFFFFFu - (unsigned)i);
    }
  }
  __syncthreads();
  int cnt = scnt; if (cnt > 4096) cnt = 4096;
  for (int i = cnt + t; i < 4096; i += 1024) cand[i] = 0ull;
  __syncthreads();
  // bitonic sort descending: key = (score_mapped, ~idx)  => score desc, idx asc
  for (int k = 2; k <= 4096; k <<= 1) {
    for (int j = k >> 1; j > 0; j >>= 1) {
      for (int i = t; i < 4096; i += 1024) {
        int ixj = i ^ j;
        if (ixj > i) {
          unsigned long long va = cand[i], vb = cand[ixj];
          bool desc = ((i & k) == 0);
          if (desc ? (va < vb) : (va > vb)) { cand[i] = vb; cand[ixj] = va; }
        }
      }
      __syncthreads();
    }
  }
  for (int i = t; i < PRE; i += 1024) {
    unsigned long long kv = cand[i];
    unsigned idx = 0xFFFFFFFFu - (unsigned)(kv & 0xFFFFFFFFull);
    float4 bb = *(const float4*)(boxes + ((size_t)n * AN + idx) * 4);
    *(float4*)(sbox + ((size_t)n * PRE + i) * 4) = bb;
    sval[n * PRE + i] = ((kv >> 32) != 0ull) ? 1 : 0;
  }
}

// ---------------- NMS suppression bitmask: 4 i-tiles per 256-thread block ----------------
__global__ __launch_bounds__(256) void k_mask(const float* __restrict__ sbox,
    unsigned long long* __restrict__ mask) {
  __shared__ float4 jb[64];
  const int t = threadIdx.x;
  const int lane = t & 63, wv = t >> 6;
  const int jt = blockIdx.x, n = blockIdx.z;
  const int it = blockIdx.y * 4 + wv;
  const int j0 = jt * 64;
  if (t < 64) {
    int jg = j0 + t;
    float4 v = make_float4(0.f, 0.f, 0.f, 0.f);
    if (jg < PRE) v = *(const float4*)(sbox + ((size_t)n * PRE + jg) * 4);
    jb[t] = v;
  }
  __syncthreads();
  const int i = it * 64 + lane;
  if (it >= NW64 || i >= PRE) return;
  float4 bi = *(const float4*)(sbox + ((size_t)n * PRE + i) * 4);
  float areaI = (bi.z - bi.x) * (bi.w - bi.y);
  unsigned long long bits = 0ull;
  #pragma unroll 4
  for (int jj = 0; jj < 64; ++jj) {
    int j = j0 + jj;
    float4 bj = jb[jj];
    float yy1 = fmaxf(bi.x, bj.x), xx1 = fmaxf(bi.y, bj.y);
    float yy2 = fminf(bi.z, bj.z), xx2 = fminf(bi.w, bj.w);
    float inter = fmaxf(yy2 - yy1, 0.f) * fmaxf(xx2 - xx1, 0.f);
    float areaJ = (bj.z - bj.x) * (bj.w - bj.y);
    float iou = inter / (areaI + areaJ - inter + 1e-9f);
    if (iou > NMS_T && j > i && j < PRE) bits |= (1ull << jj);
  }
  mask[((size_t)n * 3008 + i) * NW64 + jt] = bits;
}

// ---------------- fused: sequential greedy NMS scan + rank-compact top-300 ----------------
__global__ __launch_bounds__(256) void k_nms_final(const unsigned long long* __restrict__ mask,
    const int* __restrict__ sval, const float* __restrict__ sbox,
    float* __restrict__ rois, float* __restrict__ rind) {
  __shared__ unsigned long long kws[NW64];
  __shared__ int pref[NW64 + 1];
  const int t = threadIdx.x, n = blockIdx.x;
  // phase 1: wave 0 does the serial greedy scan (identical semantics to k_nms_seq)
  if (t < 64) {
    unsigned long long keep = 0ull;
    for (int w = 0; w < NW64; ++w) {
      int i = w * 64 + t;
      int v = (i < PRE) ? sval[n * PRE + i] : 0;
      unsigned long long m = __ballot(v != 0);
      if (t == w) keep = m;     // in-register, no LDS round-trip needed (single wave)
    }
    const unsigned long long* mrow = mask + (size_t)n * 3008 * NW64;
    unsigned long long buf[16];
    #pragma unroll
    for (int r = 0; r < 16; ++r)
      buf[r] = (t < NW64) ? mrow[(size_t)r * NW64 + t] : 0ull;
    for (int base = 0; base < PRE; base += 16) {
      #pragma unroll
      for (int r = 0; r < 16; ++r) {
        int i = base + r;
        if (i < PRE) {
          unsigned long long kb = __shfl(keep, i >> 6);
          if ((kb >> (i & 63)) & 1ull) keep &= ~buf[r];
        }
        int nx = i + 16;
        buf[r] = (nx < PRE && t < NW64) ? mrow[(size_t)nx * NW64 + t] : 0ull;
      }
    }
    if (t < NW64) kws[t] = keep;
  }
  __syncthreads();
  // phase 2: all threads — identical to k_final
  if (t == 0) {
    int s = 0;
    for (int w = 0; w < NW64; ++w) { pref[w] = s; s += __popcll(kws[w]); }
    pref[NW64] = s;
  }
  for (int e = t; e < POST * 4; e += 256) rois[(size_t)n * POST * 4 + e] = 0.f;
  for (int e = t; e < POST; e += 256) rind[(size_t)n * POST + e] = (float)n;
  __syncthreads();
  for (int i = t; i < PRE; i += 256) {
    int wd = i >> 6, b = i & 63;
    unsigned long long wv = kws[wd];
    if ((wv >> b) & 1ull) {
      int rank = pref[wd] + __popcll(wv & ((1ull << b) - 1ull));
      if (rank < POST) {
        float4 bb = *(const float4*)(sbox + ((size_t)n * PRE + i) * 4);
        *(float4*)(rois + ((size_t)n * POST + rank) * 4) = bb;
      }
    }
  }
}

// ---------------- launch (6 kernels total) ----------------
extern "C" void kernel_launch(void* const* d_in, const int* in_sizes, int n_in,
                              void* d_out, int out_size, void* d_ws, size_t ws_size,
                              hipStream_t stream) {
  const float* x  = (const float*)d_in[0];
  const float* w1 = (const float*)d_in[1];
  const float* b1 = (const float*)d_in[2];
  const float* wc = (const float*)d_in[3];
  const float* bc = (const float*)d_in[4];
  const float* wr = (const float*)d_in[5];
  const float* br = (const float*)d_in[6];
  const int* imw  = (const int*)d_in[7];
  const int* imh  = (const int*)d_in[8];
  float* out = (float*)d_out;
  char* ws = (char*)d_ws;
  float* hbuf = (float*)(ws + WS_H);
  f16* WH     = (f16*)(ws + WS_WT);
  f16* WL     = (f16*)(ws + WS_WT + 1179648);
  float* w54  = (float*)(ws + WS_W54);
  float* boxes = (float*)(ws + WS_BOXES);
  unsigned* keys = (unsigned*)(ws + WS_KEYS);
  float* sbox = (float*)(ws + WS_SBOX);
  int* sval   = (int*)(ws + WS_SVAL);
  unsigned long long* mask  = (unsigned long long*)(ws + WS_MASK);

  k_prep_all<<<2304, 256, 0, stream>>>(w1, wc, wr, WH, WL, w54, out + OUT_ANCH);
  k_conv3x3<<<dim3(91, 4, NB), 256, 0, stream>>>(x, WH, WL, b1, hbuf);
  k_heads<<<313, 256, 0, stream>>>(hbuf, w54, bc, br, imw, imh,
                                   out + OUT_CLS, out + OUT_REG, boxes, keys);
  k_select<<<NB, 1024, 0, stream>>>(keys, boxes, sbox, sval);
  k_mask<<<dim3(NW64, 12, NB), 256, 0, stream>>>(sbox, mask);
  k_nms_final<<<NB, 256, 0, stream>>>(mask, sval, sbox, out + OUT_ROIS, out + OUT_RIND);
}

// Round 5
// 1257.438 us; speedup vs baseline: 1.5910x; 1.0257x over previous
//
#include <hip/hip_runtime.h>
#include <cstdint>
#include <math.h>

// ---------------- problem constants ----------------
static constexpr int NB  = 8;
static constexpr int CC_ = 256;          // channels
static constexpr int HH  = 100, WW = 100, HW = 10000;
static constexpr int KA  = 9;
static constexpr int AN  = HW * KA;      // 90000 anchors/image
static constexpr int PRE  = 3000;
static constexpr int POST = 300;
static constexpr int NW64 = 47;          // ceil(3000/64)
static constexpr float NMS_T = 0.7f;

typedef _Float16 f16;
typedef _Float16 f16x8 __attribute__((ext_vector_type(8)));
typedef float f32x4 __attribute__((ext_vector_type(4)));

// d_out layout (float offsets)
static constexpr size_t OUT_CLS  = 0;            // 8*2*90000 = 1,440,000
static constexpr size_t OUT_REG  = 1440000;      // 8*90000*4 = 2,880,000
static constexpr size_t OUT_ROIS = 4320000;      // 2400*4
static constexpr size_t OUT_RIND = 4329600;      // 2400
static constexpr size_t OUT_ANCH = 4332000;      // 90000*4

// workspace layout (byte offsets, all 16B-aligned)
// WS_WT region holds WH (1,179,648) + WL (1,179,648): split-f16 weights in
// A-fragment order [tap9][kg8][kq4][co256][8ci].
static constexpr size_t WS_H     = 0;                          // 81,920,000
static constexpr size_t WS_WT    = 81920000;                   //  2,359,296
static constexpr size_t WS_W54   = WS_WT   + 2359296;          //     55,296
static constexpr size_t WS_BOXES = WS_W54  + 55296;            // 11,520,000
static constexpr size_t WS_KEYS  = WS_BOXES+ 11520000;         //  2,880,000
static constexpr size_t WS_SBOX  = WS_KEYS + 2880000;          //    384,000
static constexpr size_t WS_SVAL  = WS_SBOX + 384000;           //     96,000
static constexpr size_t WS_MASK  = WS_SVAL + 96000;            //  9,048,064

// anchor heights/widths per k = r_idx*3 + s_idx  (fp32 of f64-exact values)
__device__ __constant__ float AHC[9] = {
  90.50966799187809f, 181.01933598375618f, 362.03867196751236f,
  128.f, 256.f, 512.f,
  181.01933598375618f, 362.03867196751236f, 724.0773439350247f };
__device__ __constant__ float AWC[9] = {
  181.01933598375618f, 362.03867196751236f, 724.0773439350247f,
  128.f, 256.f, 512.f,
  90.50966799187809f, 181.01933598375618f, 362.03867196751236f };

// ---------------- prep: split-f16 weights (A-frag order) + head weights + anchors ----------
__global__ void k_prep_all(const float* __restrict__ w1, const float* __restrict__ wc,
                           const float* __restrict__ wr, f16* __restrict__ WH,
                           f16* __restrict__ WL, float* __restrict__ w54,
                           float* __restrict__ anch) {
  int t = blockIdx.x * 256 + threadIdx.x;
  if (t < 589824) {
    // t = (((tap*8 + kg)*4 + kq)*256 + co)*8 + cil ; ci = kg*32 + kq*8 + cil
    int cil = t & 7, co = (t >> 3) & 255, rr = t >> 11;
    int kq = rr & 3, kg = (rr >> 2) & 7, tap = rr >> 5;
    int ci = kg * 32 + kq * 8 + cil;
    float v = w1[((size_t)co * 256 + ci) * 9 + tap];
    f16 hi = (f16)v;
    float res = v - (float)hi;
    WH[t] = hi;
    WL[t] = (f16)(res * 2048.f);     // scaled-lo: exact pow2 scale, avoids f16 denorm loss
  }
  if (t < 256 * 54) {
    int ci = t / 54, j = t % 54;
    w54[t] = (j < 18) ? wc[j * 256 + ci] : wr[(j - 18) * 256 + ci];
  }
  int u = t - 256 * 54;
  if (u >= 0 && u < AN) {
    int k = u % KA; int pp = u / KA; int y = pp / WW; int x = pp % WW;
    int ri = k / 3, si = k % 3;
    double scale = (double)(8 << si);
    double r = (ri == 0) ? 0.5 : ((ri == 1) ? 1.0 : 2.0);
    double hh = 16.0 * scale * sqrt(r);
    double ww = 16.0 * scale * sqrt(1.0 / r);
    double sy = y * 16.0, sx = x * 16.0;
    anch[(size_t)u * 4 + 0] = (float)(sy + 8.0 - hh * 0.5);
    anch[(size_t)u * 4 + 1] = (float)(sx + 8.0 - ww * 0.5);
    anch[(size_t)u * 4 + 2] = (float)(sy + 8.0 + hh * 0.5);
    anch[(size_t)u * 4 + 3] = (float)(sx + 8.0 + ww * 0.5);
  }
}

// ---------------- conv 3x3 pad 1 + bias + relu — split-f16 MFMA implicit GEMM ----------------
// R13: latency fixes on R12's structure (R12 postmortem: A-frag L2 latency exposed,
// x-refetch doubled HBM, 181-pad TRIPLED bank conflicts).
//  (1) one-tap-ahead register double-buffer of A-frags (ping-pong, fully unrolled
//      -> static indexing): tap t9+1's 4 global loads issue before tap t9's MFMAs.
//  (2) XCD-colocating 1D grid: bid = (p>>3)*32 + c*8 + (p&7) so the 4 co-tiles of
//      one pixel region share bid%8 (same XCD) -> x re-reads hit that XCD's L2.
//  (3) LDS pad reverted 181->180 (R12 measured 20.1M conflicts vs R11's 6.7M).
// MFMA accumulation order UNCHANGED (kg asc, tap asc, 3-term order) — conv output
// bit-exact vs R11/R12 => selection/NMS identical.
__global__ __launch_bounds__(256, 3) void k_conv3x3(const float* __restrict__ x,
    const f16* __restrict__ WH, const f16* __restrict__ WL,
    const float* __restrict__ b1, float* __restrict__ hout) {
  __shared__ __align__(16) f16 SX[2][2][4][180][8];   // [buf][hl][kq][pix][8ci]
  const int tid = threadIdx.x;
  const int lane = tid & 63;
  const int w = tid >> 6;
  // XCD-colocating decode (bijective: 728 pixel-regions x 4 co-tiles = 2912)
  const int bid = blockIdx.x;
  const int p = ((bid >> 5) << 3) | (bid & 7);   // pixel-region 0..727
  const int cotile = (bid >> 3) & 3;             // 0..3
  const int xt_yt = p % 91;
  const int n = p / 91;
  const int xt = xt_yt % 7, yt = xt_yt / 7;
  const int x0 = xt * 16, y0 = yt * 8;
  const int wy = (w & 1) * 4;         // wave's 4-row strip within 8-row tile
  const int wc = (w >> 1) * 32;       // wave's 32-co slice within 64
  const int xb = lane & 15, kh = lane >> 4;

  // staging: threads 0..179 each own one (r,c) of the 10x18 halo tile
  const int sp = tid;
  const bool s_on = sp < 180;
  const int s_r = sp / 18, s_c = sp % 18;
  const int gy = y0 - 1 + s_r, gx = x0 - 1 + s_c;
  const bool s_ok = s_on && gy >= 0 && gy < HH && gx >= 0 && gx < WW;
  const int s_goff = s_ok ? gy * WW + gx : 0;

  const float* xn = x + (size_t)n * CC_ * HW;

  f32x4 acc1[2][4], acc2[2][4];
  #pragma unroll
  for (int a = 0; a < 2; ++a)
    #pragma unroll
    for (int b = 0; b < 4; ++b) {
      acc1[a][b] = (f32x4){0.f, 0.f, 0.f, 0.f};
      acc2[a][b] = (f32x4){0.f, 0.f, 0.f, 0.f};
    }

  float xv[16];
  auto prefetch16 = [&](int kg2, int half) {
    if (s_ok) {
      const float* bp = xn + (size_t)(kg2 * 32 + half * 16) * HW + s_goff;
      #pragma unroll
      for (int j = 0; j < 16; ++j) xv[j] = bp[(size_t)j * HW];
    } else {
      #pragma unroll
      for (int j = 0; j < 16; ++j) xv[j] = 0.f;
    }
  };
  auto commit16 = [&](int nb, int half) {
    if (s_on) {
      #pragma unroll
      for (int q = 0; q < 2; ++q) {
        f16x8 H, L;
        #pragma unroll
        for (int j = 0; j < 8; ++j) {
          float v = xv[q * 8 + j];
          f16 hi = (f16)v;
          float res = v - (float)hi;
          H[j] = hi;
          L[j] = (f16)(res * 2048.f);
        }
        *(f16x8*)&SX[nb][0][half * 2 + q][sp][0] = H;
        *(f16x8*)&SX[nb][1][half * 2 + q][sp][0] = L;
      }
    }
  };

  const int cob = cotile * 64 + wc;
  auto loadA = [&](int kg2, int t9, f16x8* ah, f16x8* al) {
    const size_t wbase = ((((size_t)t9 * 8 + kg2) * 4 + kh) * 256 + cob + xb) * 8;
    #pragma unroll
    for (int cf = 0; cf < 2; ++cf) {
      ah[cf] = *(const f16x8*)(WH + wbase + (size_t)cf * 128);  // +16 co
      al[cf] = *(const f16x8*)(WL + wbase + (size_t)cf * 128);
    }
  };

  // prologue: stage ci-group 0 (both halves)
  prefetch16(0, 0); commit16(0, 0);
  prefetch16(0, 1); commit16(0, 1);
  __syncthreads();

  for (int kg = 0; kg < 8; ++kg) {
    const int buf = kg & 1;
    const bool more = (kg < 7);
    f16x8 ah[2][2], al[2][2];           // [pingpong][cf] — static idx (unrolled)
    loadA(kg, 0, ah[0], al[0]);
    if (more) prefetch16(kg + 1, 0);    // issue early: hides under taps 0..3
    #pragma unroll
    for (int t9 = 0; t9 < 9; ++t9) {
      const int cur = t9 & 1, nxt = cur ^ 1;
      if (t9 < 8) loadA(kg, t9 + 1, ah[nxt], al[nxt]);   // one tap ahead
      const int ky = t9 / 3, kx = t9 % 3;
      f16x8 bh[4], bl[4];
      #pragma unroll
      for (int nf = 0; nf < 4; ++nf) {
        const int pixf = (wy + nf + ky) * 18 + xb + kx;
        bh[nf] = *(const f16x8*)&SX[buf][0][kh][pixf][0];
        bl[nf] = *(const f16x8*)&SX[buf][1][kh][pixf][0];
      }
      #pragma unroll
      for (int cf = 0; cf < 2; ++cf)
        #pragma unroll
        for (int nf = 0; nf < 4; ++nf) {
          acc1[cf][nf] = __builtin_amdgcn_mfma_f32_16x16x32_f16(ah[cur][cf], bh[nf], acc1[cf][nf], 0, 0, 0);
          acc2[cf][nf] = __builtin_amdgcn_mfma_f32_16x16x32_f16(ah[cur][cf], bl[nf], acc2[cf][nf], 0, 0, 0);
          acc2[cf][nf] = __builtin_amdgcn_mfma_f32_16x16x32_f16(al[cur][cf], bh[nf], acc2[cf][nf], 0, 0, 0);
        }
      if (t9 == 3 && more) {
        commit16(buf ^ 1, 0);          // write-late into the other buffer
        prefetch16(kg + 1, 1);         // issue 2nd half; hides under taps 4..8
      }
    }
    if (more) commit16(buf ^ 1, 1);
    __syncthreads();
  }

  // epilogue: combine, bias, relu, store (C/D: col=lane&15=x, row=kh*4+reg=co)
  const int xg = x0 + xb;
  #pragma unroll
  for (int cf = 0; cf < 2; ++cf)
    #pragma unroll
    for (int r = 0; r < 4; ++r) {
      const int co = cob + cf * 16 + kh * 4 + r;
      const float bias = b1[co];
      const size_t obase = (size_t)(n * CC_ + co) * HH;
      #pragma unroll
      for (int nf = 0; nf < 4; ++nf) {
        const int yg = y0 + wy + nf;
        if (yg < HH && xg < WW) {
          float v = fmaf(acc2[cf][nf][r], 0.00048828125f, acc1[cf][nf][r]) + bias;
          hout[(obase + yg) * WW + xg] = fmaxf(v, 0.f);
        }
      }
    }
}

// ---------------- 1x1 heads + decode + score keys ----------------
__global__ __launch_bounds__(256) void k_heads(const float* __restrict__ hin,
    const float* __restrict__ w54, const float* __restrict__ bc, const float* __restrict__ br,
    const int* __restrict__ imw, const int* __restrict__ imh,
    float* __restrict__ cls_out, float* __restrict__ reg_out,
    float* __restrict__ boxes, unsigned int* __restrict__ keys) {
  int gid = blockIdx.x * 256 + threadIdx.x;
  if (gid >= NB * HW) return;
  int n = gid / HW, p = gid % HW;
  float cacc[18], racc[36];
  #pragma unroll
  for (int j = 0; j < 18; ++j) cacc[j] = 0.f;
  #pragma unroll
  for (int j = 0; j < 36; ++j) racc[j] = 0.f;
  const float* hp = hin + (size_t)n * CC_ * HW + p;
  #pragma unroll 8
  for (int ci = 0; ci < CC_; ++ci) {
    float hv = hp[(size_t)ci * HW];
    const float* wrow = w54 + ci * 54;
    #pragma unroll
    for (int j = 0; j < 18; ++j) cacc[j] = fmaf(hv, wrow[j], cacc[j]);
    #pragma unroll
    for (int j = 0; j < 36; ++j) racc[j] = fmaf(hv, wrow[18 + j], racc[j]);
  }
  const float imgW = (float)imw[0], imgH = (float)imh[0];
  const int y = p / WW, xq = p % WW;
  #pragma unroll
  for (int k = 0; k < 9; ++k) {
    float c0 = cacc[2 * k] + bc[2 * k];
    float c1 = cacc[2 * k + 1] + bc[2 * k + 1];
    int a = p * 9 + k;
    cls_out[(size_t)n * 2 * AN + a]      = c0;
    cls_out[(size_t)n * 2 * AN + AN + a] = c1;
    float t0 = racc[4 * k]     + br[4 * k];
    float t1 = racc[4 * k + 1] + br[4 * k + 1];
    float t2 = racc[4 * k + 2] + br[4 * k + 2];
    float t3 = racc[4 * k + 3] + br[4 * k + 3];
    size_t ro = ((size_t)n * AN + a) * 4;
    reg_out[ro] = t0; reg_out[ro + 1] = t1; reg_out[ro + 2] = t2; reg_out[ro + 3] = t3;
    float hk = AHC[k], wk = AWC[k];
    float cy = fmaf(t0, hk, y  * 16.f + 8.f);
    float cx = fmaf(t1, wk, xq * 16.f + 8.f);
    float bh = expf(t2) * hk, bw = expf(t3) * wk;
    float y1 = cy - 0.5f * bh, x1 = cx - 0.5f * bw;
    float y2 = cy + 0.5f * bh, x2 = cx + 0.5f * bw;
    y1 = fminf(fmaxf(y1, 0.f), imgH); y2 = fminf(fmaxf(y2, 0.f), imgH);
    x1 = fminf(fmaxf(x1, 0.f), imgW); x2 = fminf(fmaxf(x2, 0.f), imgW);
    bool valid = (y2 - y1 >= 16.f) && (x2 - x1 >= 16.f);
    boxes[ro] = y1; boxes[ro + 1] = x1; boxes[ro + 2] = y2; boxes[ro + 3] = x2;
    float dc = c1 - c0;                       // monotone in softmax fg
    unsigned u = __float_as_uint(dc);
    u = (u & 0x80000000u) ? ~u : (u | 0x80000000u);
    keys[(size_t)n * AN + a] = valid ? u : 0u;
  }
}

// ---------------- per-image stable top-3000 selection (monolithic, proven R3/R7) ----------------
__global__ __launch_bounds__(1024) void k_select(const unsigned* __restrict__ keys,
    const float* __restrict__ boxes, float* __restrict__ sbox, int* __restrict__ sval) {
  __shared__ unsigned hist[4][1024];
  __shared__ unsigned long long cand[4096];
  __shared__ int sB1, sA1, sB2, scnt;
  const int t = threadIdx.x;
  const int n = blockIdx.x;
  const unsigned* kp = keys + (size_t)n * AN;
  for (int i = t; i < 4096; i += 1024) ((unsigned*)hist)[i] = 0;
  __syncthreads();
  const int rep = (t >> 6) & 3;
  for (int i = t; i < AN; i += 1024) atomicAdd(&hist[rep][kp[i] >> 22], 1u);
  __syncthreads();
  unsigned myc = hist[0][t] + hist[1][t] + hist[2][t] + hist[3][t];
  __syncthreads();
  hist[0][t] = myc;
  __syncthreads();
  for (int off = 1; off < 1024; off <<= 1) {
    unsigned add = (t + off < 1024) ? hist[0][t + off] : 0;
    __syncthreads();
    hist[0][t] += add;
    __syncthreads();
  }
  unsigned incl = hist[0][t];
  unsigned above = incl - myc;
  if (above < (unsigned)PRE && incl >= (unsigned)PRE && myc > 0) { sB1 = t; sA1 = (int)above; }
  __syncthreads();
  const int B1 = sB1, A1 = sA1;
  __syncthreads();
  hist[0][t] = 0;
  __syncthreads();
  for (int i = t; i < AN; i += 1024) {
    unsigned k32 = kp[i];
    if ((int)(k32 >> 22) == B1) atomicAdd(&hist[0][(k32 >> 12) & 1023u], 1u);
  }
  __syncthreads();
  myc = hist[0][t];
  __syncthreads();
  for (int off = 1; off < 1024; off <<= 1) {
    unsigned add = (t + off < 1024) ? hist[0][t + off] : 0;
    __syncthreads();
    hist[0][t] += add;
    __syncthreads();
  }
  incl = hist[0][t]; above = incl - myc;
  const int target = PRE - A1;
  if ((int)above < target && (int)incl >= target && myc > 0) sB2 = t;
  if (t == 0) scnt = 0;
  __syncthreads();
  const int B2 = sB2;
  for (int i = t; i < AN; i += 1024) {
    unsigned k32 = kp[i];
    int b1 = (int)(k32 >> 22);
    bool sel = (b1 > B1) || (b1 == B1 && (int)((k32 >> 12) & 1023u) >= B2);
    if (sel) {
      int pos = atomicAdd(&scnt, 1);
      if (pos < 4096)
        cand[pos] = ((unsigned long long)k32 << 32) | (unsigned long long)(0xFFFFFFFFu - (unsigned)i);
    }
  }
  __syncthreads();
  int cnt = scnt; if (cnt > 4096) cnt = 4096;
  for (int i = cnt + t; i < 4096; i += 1024) cand[i] = 0ull;
  __syncthreads();
  // bitonic sort descending: key = (score_mapped, ~idx)  => score desc, idx asc
  for (int k = 2; k <= 4096; k <<= 1) {
    for (int j = k >> 1; j > 0; j >>= 1) {
      for (int i = t; i < 4096; i += 1024) {
        int ixj = i ^ j;
        if (ixj > i) {
          unsigned long long va = cand[i], vb = cand[ixj];
          bool desc = ((i & k) == 0);
          if (desc ? (va < vb) : (va > vb)) { cand[i] = vb; cand[ixj] = va; }
        }
      }
      __syncthreads();
    }
  }
  for (int i = t; i < PRE; i += 1024) {
    unsigned long long kv = cand[i];
    unsigned idx = 0xFFFFFFFFu - (unsigned)(kv & 0xFFFFFFFFull);
    float4 bb = *(const float4*)(boxes + ((size_t)n * AN + idx) * 4);
    *(float4*)(sbox + ((size_t)n * PRE + i) * 4) = bb;
    sval[n * PRE + i] = ((kv >> 32) != 0ull) ? 1 : 0;
  }
}

// ---------------- NMS suppression bitmask: 4 i-tiles per 256-thread block ----------------
__global__ __launch_bounds__(256) void k_mask(const float* __restrict__ sbox,
    unsigned long long* __restrict__ mask) {
  __shared__ float4 jb[64];
  const int t = threadIdx.x;
  const int lane = t & 63, wv = t >> 6;
  const int jt = blockIdx.x, n = blockIdx.z;
  const int it = blockIdx.y * 4 + wv;
  const int j0 = jt * 64;
  if (t < 64) {
    int jg = j0 + t;
    float4 v = make_float4(0.f, 0.f, 0.f, 0.f);
    if (jg < PRE) v = *(const float4*)(sbox + ((size_t)n * PRE + jg) * 4);
    jb[t] = v;
  }
  __syncthreads();
  const int i = it * 64 + lane;
  if (it >= NW64 || i >= PRE) return;
  float4 bi = *(const float4*)(sbox + ((size_t)n * PRE + i) * 4);
  float areaI = (bi.z - bi.x) * (bi.w - bi.y);
  unsigned long long bits = 0ull;
  #pragma unroll 4
  for (int jj = 0; jj < 64; ++jj) {
    int j = j0 + jj;
    float4 bj = jb[jj];
    float yy1 = fmaxf(bi.x, bj.x), xx1 = fmaxf(bi.y, bj.y);
    float yy2 = fminf(bi.z, bj.z), xx2 = fminf(bi.w, bj.w);
    float inter = fmaxf(yy2 - yy1, 0.f) * fmaxf(xx2 - xx1, 0.f);
    float areaJ = (bj.z - bj.x) * (bj.w - bj.y);
    float iou = inter / (areaI + areaJ - inter + 1e-9f);
    if (iou > NMS_T && j > i && j < PRE) bits |= (1ull << jj);
  }
  mask[((size_t)n * 3008 + i) * NW64 + jt] = bits;
}

// ---------------- fused: sequential greedy NMS scan + rank-compact top-300 ----------------
__global__ __launch_bounds__(256) void k_nms_final(const unsigned long long* __restrict__ mask,
    const int* __restrict__ sval, const float* __restrict__ sbox,
    float* __restrict__ rois, float* __restrict__ rind) {
  __shared__ unsigned long long kws[NW64];
  __shared__ int pref[NW64 + 1];
  const int t = threadIdx.x, n = blockIdx.x;
  // phase 1: wave 0 does the serial greedy scan (identical semantics to k_nms_seq)
  if (t < 64) {
    unsigned long long keep = 0ull;
    for (int w = 0; w < NW64; ++w) {
      int i = w * 64 + t;
      int v = (i < PRE) ? sval[n * PRE + i] : 0;
      unsigned long long m = __ballot(v != 0);
      if (t == w) keep = m;     // in-register, no LDS round-trip needed (single wave)
    }
    const unsigned long long* mrow = mask + (size_t)n * 3008 * NW64;
    unsigned long long buf[16];
    #pragma unroll
    for (int r = 0; r < 16; ++r)
      buf[r] = (t < NW64) ? mrow[(size_t)r * NW64 + t] : 0ull;
    for (int base = 0; base < PRE; base += 16) {
      #pragma unroll
      for (int r = 0; r < 16; ++r) {
        int i = base + r;
        if (i < PRE) {
          unsigned long long kb = __shfl(keep, i >> 6);
          if ((kb >> (i & 63)) & 1ull) keep &= ~buf[r];
        }
        int nx = i + 16;
        buf[r] = (nx < PRE && t < NW64) ? mrow[(size_t)nx * NW64 + t] : 0ull;
      }
    }
    if (t < NW64) kws[t] = keep;
  }
  __syncthreads();
  // phase 2: all threads — identical to k_final
  if (t == 0) {
    int s = 0;
    for (int w = 0; w < NW64; ++w) { pref[w] = s; s += __popcll(kws[w]); }
    pref[NW64] = s;
  }
  for (int e = t; e < POST * 4; e += 256) rois[(size_t)n * POST * 4 + e] = 0.f;
  for (int e = t; e < POST; e += 256) rind[(size_t)n * POST + e] = (float)n;
  __syncthreads();
  for (int i = t; i < PRE; i += 256) {
    int wd = i >> 6, b = i & 63;
    unsigned long long wv = kws[wd];
    if ((wv >> b) & 1ull) {
      int rank = pref[wd] + __popcll(wv & ((1ull << b) - 1ull));
      if (rank < POST) {
        float4 bb = *(const float4*)(sbox + ((size_t)n * PRE + i) * 4);
        *(float4*)(rois + ((size_t)n * POST + rank) * 4) = bb;
      }
    }
  }
}

// ---------------- launch (6 kernels total) ----------------
extern "C" void kernel_launch(void* const* d_in, const int* in_sizes, int n_in,
                              void* d_out, int out_size, void* d_ws, size_t ws_size,
                              hipStream_t stream) {
  const float* x  = (const float*)d_in[0];
  const float* w1 = (const float*)d_in[1];
  const float* b1 = (const float*)d_in[2];
  const float* wc = (const float*)d_in[3];
  const float* bc = (const float*)d_in[4];
  const float* wr = (const float*)d_in[5];
  const float* br = (const float*)d_in[6];
  const int* imw  = (const int*)d_in[7];
  const int* imh  = (const int*)d_in[8];
  float* out = (float*)d_out;
  char* ws = (char*)d_ws;
  float* hbuf = (float*)(ws + WS_H);
  f16* WH     = (f16*)(ws + WS_WT);
  f16* WL     = (f16*)(ws + WS_WT + 1179648);
  float* w54  = (float*)(ws + WS_W54);
  float* boxes = (float*)(ws + WS_BOXES);
  unsigned* keys = (unsigned*)(ws + WS_KEYS);
  float* sbox = (float*)(ws + WS_SBOX);
  int* sval   = (int*)(ws + WS_SVAL);
  unsigned long long* mask  = (unsigned long long*)(ws + WS_MASK);

  k_prep_all<<<2304, 256, 0, stream>>>(w1, wc, wr, WH, WL, w54, out + OUT_ANCH);
  k_conv3x3<<<2912, 256, 0, stream>>>(x, WH, WL, b1, hbuf);
  k_heads<<<313, 256, 0, stream>>>(hbuf, w54, bc, br, imw, imh,
                                   out + OUT_CLS, out + OUT_REG, boxes, keys);
  k_select<<<NB, 1024, 0, stream>>>(keys, boxes, sbox, sval);
  k_mask<<<dim3(NW64, 12, NB), 256, 0, stream>>>(sbox, mask);
  k_nms_final<<<NB, 256, 0, stream>>>(mask, sval, sbox, out + OUT_ROIS, out + OUT_RIND);
}

// Round 6
// 1107.570 us; speedup vs baseline: 1.8063x; 1.1353x over previous
//
#include <hip/hip_runtime.h>
#include <cstdint>
#include <math.h>

// ---------------- problem constants ----------------
static constexpr int NB  = 8;
static constexpr int CC_ = 256;          // channels
static constexpr int HH  = 100, WW = 100, HW = 10000;
static constexpr int KA  = 9;
static constexpr int AN  = HW * KA;      // 90000 anchors/image
static constexpr int PRE  = 3000;
static constexpr int POST = 300;
static constexpr int NW64 = 47;          // ceil(3000/64)
static constexpr float NMS_T = 0.7f;

typedef _Float16 f16;
typedef _Float16 f16x8 __attribute__((ext_vector_type(8)));
typedef float f32x4 __attribute__((ext_vector_type(4)));

// d_out layout (float offsets)
static constexpr size_t OUT_CLS  = 0;            // 8*2*90000 = 1,440,000
static constexpr size_t OUT_REG  = 1440000;      // 8*90000*4 = 2,880,000
static constexpr size_t OUT_ROIS = 4320000;      // 2400*4
static constexpr size_t OUT_RIND = 4329600;      // 2400
static constexpr size_t OUT_ANCH = 4332000;      // 90000*4

// workspace layout (byte offsets, all 16B-aligned)
// WS_WT region holds WH (1,179,648) + WL (1,179,648): split-f16 weights in
// A-fragment order [tap9][kg8][kq4][co256][8ci].
static constexpr size_t WS_H     = 0;                          // 81,920,000
static constexpr size_t WS_WT    = 81920000;                   //  2,359,296
static constexpr size_t WS_W54   = WS_WT   + 2359296;          //     55,296
static constexpr size_t WS_BOXES = WS_W54  + 55296;            // 11,520,000
static constexpr size_t WS_KEYS  = WS_BOXES+ 11520000;         //  2,880,000
static constexpr size_t WS_SBOX  = WS_KEYS + 2880000;          //    384,000
static constexpr size_t WS_SVAL  = WS_SBOX + 384000;           //     96,000
static constexpr size_t WS_MASK  = WS_SVAL + 96000;            //  9,048,064

// anchor heights/widths per k = r_idx*3 + s_idx  (fp32 of f64-exact values)
__device__ __constant__ float AHC[9] = {
  90.50966799187809f, 181.01933598375618f, 362.03867196751236f,
  128.f, 256.f, 512.f,
  181.01933598375618f, 362.03867196751236f, 724.0773439350247f };
__device__ __constant__ float AWC[9] = {
  181.01933598375618f, 362.03867196751236f, 724.0773439350247f,
  128.f, 256.f, 512.f,
  90.50966799187809f, 181.01933598375618f, 362.03867196751236f };

// ---------------- prep: split-f16 weights (A-frag order) + head weights + anchors ----------
__global__ void k_prep_all(const float* __restrict__ w1, const float* __restrict__ wc,
                           const float* __restrict__ wr, f16* __restrict__ WH,
                           f16* __restrict__ WL, float* __restrict__ w54,
                           float* __restrict__ anch) {
  int t = blockIdx.x * 256 + threadIdx.x;
  if (t < 589824) {
    // t = (((tap*8 + kg)*4 + kq)*256 + co)*8 + cil ; ci = kg*32 + kq*8 + cil
    int cil = t & 7, co = (t >> 3) & 255, rr = t >> 11;
    int kq = rr & 3, kg = (rr >> 2) & 7, tap = rr >> 5;
    int ci = kg * 32 + kq * 8 + cil;
    float v = w1[((size_t)co * 256 + ci) * 9 + tap];
    f16 hi = (f16)v;
    float res = v - (float)hi;
    WH[t] = hi;
    WL[t] = (f16)(res * 2048.f);     // scaled-lo: exact pow2 scale, avoids f16 denorm loss
  }
  if (t < 256 * 54) {
    int ci = t / 54, j = t % 54;
    w54[t] = (j < 18) ? wc[j * 256 + ci] : wr[(j - 18) * 256 + ci];
  }
  int u = t - 256 * 54;
  if (u >= 0 && u < AN) {
    int k = u % KA; int pp = u / KA; int y = pp / WW; int x = pp % WW;
    int ri = k / 3, si = k % 3;
    double scale = (double)(8 << si);
    double r = (ri == 0) ? 0.5 : ((ri == 1) ? 1.0 : 2.0);
    double hh = 16.0 * scale * sqrt(r);
    double ww = 16.0 * scale * sqrt(1.0 / r);
    double sy = y * 16.0, sx = x * 16.0;
    anch[(size_t)u * 4 + 0] = (float)(sy + 8.0 - hh * 0.5);
    anch[(size_t)u * 4 + 1] = (float)(sx + 8.0 - ww * 0.5);
    anch[(size_t)u * 4 + 2] = (float)(sy + 8.0 + hh * 0.5);
    anch[(size_t)u * 4 + 3] = (float)(sx + 8.0 + ww * 0.5);
  }
}

// ---------------- conv 3x3 pad 1 + bias + relu — split-f16 MFMA implicit GEMM ----------------
// R14 (postmortem R13: VGPR_Count=84 proved the compiler SANK all prefetches —
// the source-level ping-pong never materialized; LDS reads 72 b128/kg/wave ~130us/CU):
//  (1) sched_barrier(0) fences pin the A ping-pong loads and x-prefetch issues
//      where written — the compiler may interleave within a region but not sink
//      loads past a fence.
//  (2) kx-major tap order + 6-row register cache rh/rl[6]: LDS reads 72->36 per
//      kg per wave (taps with different ky share rows; b128 reads now loaded once).
//      NOTE: this REORDERS per-accumulator tap summation (0,3,6,1,4,7,2,5,8) —
//      ~1e-7 perturbation vs R13 (R11 survived 1e-6). If absmax moves, revert.
//  (3) hi/lo 3-term order per tap, kg-major order, staging, epilogue: unchanged.
__global__ __launch_bounds__(256, 3) void k_conv3x3(const float* __restrict__ x,
    const f16* __restrict__ WH, const f16* __restrict__ WL,
    const float* __restrict__ b1, float* __restrict__ hout) {
  __shared__ __align__(16) f16 SX[2][2][4][180][8];   // [buf][hl][kq][pix][8ci]
  const int tid = threadIdx.x;
  const int lane = tid & 63;
  const int w = tid >> 6;
  // XCD-colocating decode (bijective: 728 pixel-regions x 4 co-tiles = 2912)
  const int bid = blockIdx.x;
  const int p = ((bid >> 5) << 3) | (bid & 7);   // pixel-region 0..727
  const int cotile = (bid >> 3) & 3;             // 0..3
  const int xt_yt = p % 91;
  const int n = p / 91;
  const int xt = xt_yt % 7, yt = xt_yt / 7;
  const int x0 = xt * 16, y0 = yt * 8;
  const int wy = (w & 1) * 4;         // wave's 4-row strip within 8-row tile
  const int wc = (w >> 1) * 32;       // wave's 32-co slice within 64
  const int xb = lane & 15, kh = lane >> 4;

  // staging: threads 0..179 each own one (r,c) of the 10x18 halo tile
  const int sp = tid;
  const bool s_on = sp < 180;
  const int s_r = sp / 18, s_c = sp % 18;
  const int gy = y0 - 1 + s_r, gx = x0 - 1 + s_c;
  const bool s_ok = s_on && gy >= 0 && gy < HH && gx >= 0 && gx < WW;
  const int s_goff = s_ok ? gy * WW + gx : 0;

  const float* xn = x + (size_t)n * CC_ * HW;

  f32x4 acc1[2][4], acc2[2][4];
  #pragma unroll
  for (int a = 0; a < 2; ++a)
    #pragma unroll
    for (int b = 0; b < 4; ++b) {
      acc1[a][b] = (f32x4){0.f, 0.f, 0.f, 0.f};
      acc2[a][b] = (f32x4){0.f, 0.f, 0.f, 0.f};
    }

  float xv[16];
  auto prefetch16 = [&](int kg2, int half) {
    if (s_ok) {
      const float* bp = xn + (size_t)(kg2 * 32 + half * 16) * HW + s_goff;
      #pragma unroll
      for (int j = 0; j < 16; ++j) xv[j] = bp[(size_t)j * HW];
    } else {
      #pragma unroll
      for (int j = 0; j < 16; ++j) xv[j] = 0.f;
    }
  };
  auto commit16 = [&](int nb, int half) {
    if (s_on) {
      #pragma unroll
      for (int q = 0; q < 2; ++q) {
        f16x8 H, L;
        #pragma unroll
        for (int j = 0; j < 8; ++j) {
          float v = xv[q * 8 + j];
          f16 hi = (f16)v;
          float res = v - (float)hi;
          H[j] = hi;
          L[j] = (f16)(res * 2048.f);
        }
        *(f16x8*)&SX[nb][0][half * 2 + q][sp][0] = H;
        *(f16x8*)&SX[nb][1][half * 2 + q][sp][0] = L;
      }
    }
  };

  const int cob = cotile * 64 + wc;
  auto loadA = [&](int kg2, int tap, f16x8* ah, f16x8* al) {
    const size_t wbase = ((((size_t)tap * 8 + kg2) * 4 + kh) * 256 + cob + xb) * 8;
    #pragma unroll
    for (int cf = 0; cf < 2; ++cf) {
      ah[cf] = *(const f16x8*)(WH + wbase + (size_t)cf * 128);  // +16 co
      al[cf] = *(const f16x8*)(WL + wbase + (size_t)cf * 128);
    }
  };

  // prologue: stage ci-group 0 (both halves)
  prefetch16(0, 0); commit16(0, 0);
  prefetch16(0, 1); commit16(0, 1);
  __syncthreads();

  for (int kg = 0; kg < 8; ++kg) {
    const int buf = kg & 1;
    const bool more = (kg < 7);
    f16x8 ah[2][2], al[2][2];           // [pingpong][cf] — static idx (unrolled)
    loadA(kg, 0, ah[0], al[0]);         // s=0 is (kx0,ky0) -> tap 0
    if (more) prefetch16(kg + 1, 0);    // issue early: hides under kx=0..1 MFMAs
    __builtin_amdgcn_sched_barrier(0);  // pin: loads issued before any MFMA below
    #pragma unroll
    for (int kx = 0; kx < 3; ++kx) {
      // 6-row B cache for this kx (rows wy..wy+5 cover all ky windows)
      f16x8 rh[6], rl[6];
      #pragma unroll
      for (int r = 0; r < 6; ++r) {
        const int pixf = (wy + r) * 18 + xb + kx;
        rh[r] = *(const f16x8*)&SX[buf][0][kh][pixf][0];
        rl[r] = *(const f16x8*)&SX[buf][1][kh][pixf][0];
      }
      #pragma unroll
      for (int ky = 0; ky < 3; ++ky) {
        const int s = kx * 3 + ky;       // processing order
        const int cur = s & 1;
        if (s < 8) {                     // A ping-pong: issue next tap's frags
          const int s2 = s + 1;
          loadA(kg, (s2 % 3) * 3 + s2 / 3, ah[cur ^ 1], al[cur ^ 1]);
        }
        __builtin_amdgcn_sched_barrier(0);  // pin: next-A issued before this MFMA pack
        #pragma unroll
        for (int cf = 0; cf < 2; ++cf)
          #pragma unroll
          for (int nf = 0; nf < 4; ++nf) {
            acc1[cf][nf] = __builtin_amdgcn_mfma_f32_16x16x32_f16(ah[cur][cf], rh[nf + ky], acc1[cf][nf], 0, 0, 0);
            acc2[cf][nf] = __builtin_amdgcn_mfma_f32_16x16x32_f16(ah[cur][cf], rl[nf + ky], acc2[cf][nf], 0, 0, 0);
            acc2[cf][nf] = __builtin_amdgcn_mfma_f32_16x16x32_f16(al[cur][cf], rh[nf + ky], acc2[cf][nf], 0, 0, 0);
          }
      }
      if (kx == 1 && more) {
        commit16(buf ^ 1, 0);            // write-late (xv landed ~2 kx blocks ago)
        prefetch16(kg + 1, 1);           // issue 2nd half; hides under kx=2
        __builtin_amdgcn_sched_barrier(0);
      }
    }
    if (more) commit16(buf ^ 1, 1);
    __syncthreads();
  }

  // epilogue: combine, bias, relu, store (C/D: col=lane&15=x, row=kh*4+reg=co)
  const int xg = x0 + xb;
  #pragma unroll
  for (int cf = 0; cf < 2; ++cf)
    #pragma unroll
    for (int r = 0; r < 4; ++r) {
      const int co = cob + cf * 16 + kh * 4 + r;
      const float bias = b1[co];
      const size_t obase = (size_t)(n * CC_ + co) * HH;
      #pragma unroll
      for (int nf = 0; nf < 4; ++nf) {
        const int yg = y0 + wy + nf;
        if (yg < HH && xg < WW) {
          float v = fmaf(acc2[cf][nf][r], 0.00048828125f, acc1[cf][nf][r]) + bias;
          hout[(obase + yg) * WW + xg] = fmaxf(v, 0.f);
        }
      }
    }
}

// ---------------- 1x1 heads + decode + score keys ----------------
__global__ __launch_bounds__(256) void k_heads(const float* __restrict__ hin,
    const float* __restrict__ w54, const float* __restrict__ bc, const float* __restrict__ br,
    const int* __restrict__ imw, const int* __restrict__ imh,
    float* __restrict__ cls_out, float* __restrict__ reg_out,
    float* __restrict__ boxes, unsigned int* __restrict__ keys) {
  int gid = blockIdx.x * 256 + threadIdx.x;
  if (gid >= NB * HW) return;
  int n = gid / HW, p = gid % HW;
  float cacc[18], racc[36];
  #pragma unroll
  for (int j = 0; j < 18; ++j) cacc[j] = 0.f;
  #pragma unroll
  for (int j = 0; j < 36; ++j) racc[j] = 0.f;
  const float* hp = hin + (size_t)n * CC_ * HW + p;
  #pragma unroll 8
  for (int ci = 0; ci < CC_; ++ci) {
    float hv = hp[(size_t)ci * HW];
    const float* wrow = w54 + ci * 54;
    #pragma unroll
    for (int j = 0; j < 18; ++j) cacc[j] = fmaf(hv, wrow[j], cacc[j]);
    #pragma unroll
    for (int j = 0; j < 36; ++j) racc[j] = fmaf(hv, wrow[18 + j], racc[j]);
  }
  const float imgW = (float)imw[0], imgH = (float)imh[0];
  const int y = p / WW, xq = p % WW;
  #pragma unroll
  for (int k = 0; k < 9; ++k) {
    float c0 = cacc[2 * k] + bc[2 * k];
    float c1 = cacc[2 * k + 1] + bc[2 * k + 1];
    int a = p * 9 + k;
    cls_out[(size_t)n * 2 * AN + a]      = c0;
    cls_out[(size_t)n * 2 * AN + AN + a] = c1;
    float t0 = racc[4 * k]     + br[4 * k];
    float t1 = racc[4 * k + 1] + br[4 * k + 1];
    float t2 = racc[4 * k + 2] + br[4 * k + 2];
    float t3 = racc[4 * k + 3] + br[4 * k + 3];
    size_t ro = ((size_t)n * AN + a) * 4;
    reg_out[ro] = t0; reg_out[ro + 1] = t1; reg_out[ro + 2] = t2; reg_out[ro + 3] = t3;
    float hk = AHC[k], wk = AWC[k];
    float cy = fmaf(t0, hk, y  * 16.f + 8.f);
    float cx = fmaf(t1, wk, xq * 16.f + 8.f);
    float bh = expf(t2) * hk, bw = expf(t3) * wk;
    float y1 = cy - 0.5f * bh, x1 = cx - 0.5f * bw;
    float y2 = cy + 0.5f * bh, x2 = cx + 0.5f * bw;
    y1 = fminf(fmaxf(y1, 0.f), imgH); y2 = fminf(fmaxf(y2, 0.f), imgH);
    x1 = fminf(fmaxf(x1, 0.f), imgW); x2 = fminf(fmaxf(x2, 0.f), imgW);
    bool valid = (y2 - y1 >= 16.f) && (x2 - x1 >= 16.f);
    boxes[ro] = y1; boxes[ro + 1] = x1; boxes[ro + 2] = y2; boxes[ro + 3] = x2;
    float dc = c1 - c0;                       // monotone in softmax fg
    unsigned u = __float_as_uint(dc);
    u = (u & 0x80000000u) ? ~u : (u | 0x80000000u);
    keys[(size_t)n * AN + a] = valid ? u : 0u;
  }
}

// ---------------- per-image stable top-3000 selection (monolithic, proven R3/R7) ----------------
__global__ __launch_bounds__(1024) void k_select(const unsigned* __restrict__ keys,
    const float* __restrict__ boxes, float* __restrict__ sbox, int* __restrict__ sval) {
  __shared__ unsigned hist[4][1024];
  __shared__ unsigned long long cand[4096];
  __shared__ int sB1, sA1, sB2, scnt;
  const int t = threadIdx.x;
  const int n = blockIdx.x;
  const unsigned* kp = keys + (size_t)n * AN;
  for (int i = t; i < 4096; i += 1024) ((unsigned*)hist)[i] = 0;
  __syncthreads();
  const int rep = (t >> 6) & 3;
  for (int i = t; i < AN; i += 1024) atomicAdd(&hist[rep][kp[i] >> 22], 1u);
  __syncthreads();
  unsigned myc = hist[0][t] + hist[1][t] + hist[2][t] + hist[3][t];
  __syncthreads();
  hist[0][t] = myc;
  __syncthreads();
  for (int off = 1; off < 1024; off <<= 1) {
    unsigned add = (t + off < 1024) ? hist[0][t + off] : 0;
    __syncthreads();
    hist[0][t] += add;
    __syncthreads();
  }
  unsigned incl = hist[0][t];
  unsigned above = incl - myc;
  if (above < (unsigned)PRE && incl >= (unsigned)PRE && myc > 0) { sB1 = t; sA1 = (int)above; }
  __syncthreads();
  const int B1 = sB1, A1 = sA1;
  __syncthreads();
  hist[0][t] = 0;
  __syncthreads();
  for (int i = t; i < AN; i += 1024) {
    unsigned k32 = kp[i];
    if ((int)(k32 >> 22) == B1) atomicAdd(&hist[0][(k32 >> 12) & 1023u], 1u);
  }
  __syncthreads();
  myc = hist[0][t];
  __syncthreads();
  for (int off = 1; off < 1024; off <<= 1) {
    unsigned add = (t + off < 1024) ? hist[0][t + off] : 0;
    __syncthreads();
    hist[0][t] += add;
    __syncthreads();
  }
  incl = hist[0][t]; above = incl - myc;
  const int target = PRE - A1;
  if ((int)above < target && (int)incl >= target && myc > 0) sB2 = t;
  if (t == 0) scnt = 0;
  __syncthreads();
  const int B2 = sB2;
  for (int i = t; i < AN; i += 1024) {
    unsigned k32 = kp[i];
    int b1 = (int)(k32 >> 22);
    bool sel = (b1 > B1) || (b1 == B1 && (int)((k32 >> 12) & 1023u) >= B2);
    if (sel) {
      int pos = atomicAdd(&scnt, 1);
      if (pos < 4096)
        cand[pos] = ((unsigned long long)k32 << 32) | (unsigned long long)(0xFFFFFFFFu - (unsigned)i);
    }
  }
  __syncthreads();
  int cnt = scnt; if (cnt > 4096) cnt = 4096;
  for (int i = cnt + t; i < 4096; i += 1024) cand[i] = 0ull;
  __syncthreads();
  // bitonic sort descending: key = (score_mapped, ~idx)  => score desc, idx asc
  for (int k = 2; k <= 4096; k <<= 1) {
    for (int j = k >> 1; j > 0; j >>= 1) {
      for (int i = t; i < 4096; i += 1024) {
        int ixj = i ^ j;
        if (ixj > i) {
          unsigned long long va = cand[i], vb = cand[ixj];
          bool desc = ((i & k) == 0);
          if (desc ? (va < vb) : (va > vb)) { cand[i] = vb; cand[ixj] = va; }
        }
      }
      __syncthreads();
    }
  }
  for (int i = t; i < PRE; i += 1024) {
    unsigned long long kv = cand[i];
    unsigned idx = 0xFFFFFFFFu - (unsigned)(kv & 0xFFFFFFFFull);
    float4 bb = *(const float4*)(boxes + ((size_t)n * AN + idx) * 4);
    *(float4*)(sbox + ((size_t)n * PRE + i) * 4) = bb;
    sval[n * PRE + i] = ((kv >> 32) != 0ull) ? 1 : 0;
  }
}

// ---------------- NMS suppression bitmask: 4 i-tiles per 256-thread block ----------------
__global__ __launch_bounds__(256) void k_mask(const float* __restrict__ sbox,
    unsigned long long* __restrict__ mask) {
  __shared__ float4 jb[64];
  const int t = threadIdx.x;
  const int lane = t & 63, wv = t >> 6;
  const int jt = blockIdx.x, n = blockIdx.z;
  const int it = blockIdx.y * 4 + wv;
  const int j0 = jt * 64;
  if (t < 64) {
    int jg = j0 + t;
    float4 v = make_float4(0.f, 0.f, 0.f, 0.f);
    if (jg < PRE) v = *(const float4*)(sbox + ((size_t)n * PRE + jg) * 4);
    jb[t] = v;
  }
  __syncthreads();
  const int i = it * 64 + lane;
  if (it >= NW64 || i >= PRE) return;
  float4 bi = *(const float4*)(sbox + ((size_t)n * PRE + i) * 4);
  float areaI = (bi.z - bi.x) * (bi.w - bi.y);
  unsigned long long bits = 0ull;
  #pragma unroll 4
  for (int jj = 0; jj < 64; ++jj) {
    int j = j0 + jj;
    float4 bj = jb[jj];
    float yy1 = fmaxf(bi.x, bj.x), xx1 = fmaxf(bi.y, bj.y);
    float yy2 = fminf(bi.z, bj.z), xx2 = fminf(bi.w, bj.w);
    float inter = fmaxf(yy2 - yy1, 0.f) * fmaxf(xx2 - xx1, 0.f);
    float areaJ = (bj.z - bj.x) * (bj.w - bj.y);
    float iou = inter / (areaI + areaJ - inter + 1e-9f);
    if (iou > NMS_T && j > i && j < PRE) bits |= (1ull << jj);
  }
  mask[((size_t)n * 3008 + i) * NW64 + jt] = bits;
}

// ---------------- fused: sequential greedy NMS scan + rank-compact top-300 ----------------
__global__ __launch_bounds__(256) void k_nms_final(const unsigned long long* __restrict__ mask,
    const int* __restrict__ sval, const float* __restrict__ sbox,
    float* __restrict__ rois, float* __restrict__ rind) {
  __shared__ unsigned long long kws[NW64];
  __shared__ int pref[NW64 + 1];
  const int t = threadIdx.x, n = blockIdx.x;
  // phase 1: wave 0 does the serial greedy scan (identical semantics to k_nms_seq)
  if (t < 64) {
    unsigned long long keep = 0ull;
    for (int w = 0; w < NW64; ++w) {
      int i = w * 64 + t;
      int v = (i < PRE) ? sval[n * PRE + i] : 0;
      unsigned long long m = __ballot(v != 0);
      if (t == w) keep = m;     // in-register, no LDS round-trip needed (single wave)
    }
    const unsigned long long* mrow = mask + (size_t)n * 3008 * NW64;
    unsigned long long buf[16];
    #pragma unroll
    for (int r = 0; r < 16; ++r)
      buf[r] = (t < NW64) ? mrow[(size_t)r * NW64 + t] : 0ull;
    for (int base = 0; base < PRE; base += 16) {
      #pragma unroll
      for (int r = 0; r < 16; ++r) {
        int i = base + r;
        if (i < PRE) {
          unsigned long long kb = __shfl(keep, i >> 6);
          if ((kb >> (i & 63)) & 1ull) keep &= ~buf[r];
        }
        int nx = i + 16;
        buf[r] = (nx < PRE && t < NW64) ? mrow[(size_t)nx * NW64 + t] : 0ull;
      }
    }
    if (t < NW64) kws[t] = keep;
  }
  __syncthreads();
  // phase 2: all threads — identical to k_final
  if (t == 0) {
    int s = 0;
    for (int w = 0; w < NW64; ++w) { pref[w] = s; s += __popcll(kws[w]); }
    pref[NW64] = s;
  }
  for (int e = t; e < POST * 4; e += 256) rois[(size_t)n * POST * 4 + e] = 0.f;
  for (int e = t; e < POST; e += 256) rind[(size_t)n * POST + e] = (float)n;
  __syncthreads();
  for (int i = t; i < PRE; i += 256) {
    int wd = i >> 6, b = i & 63;
    unsigned long long wv = kws[wd];
    if ((wv >> b) & 1ull) {
      int rank = pref[wd] + __popcll(wv & ((1ull << b) - 1ull));
      if (rank < POST) {
        float4 bb = *(const float4*)(sbox + ((size_t)n * PRE + i) * 4);
        *(float4*)(rois + ((size_t)n * POST + rank) * 4) = bb;
      }
    }
  }
}

// ---------------- launch (6 kernels total) ----------------
extern "C" void kernel_launch(void* const* d_in, const int* in_sizes, int n_in,
                              void* d_out, int out_size, void* d_ws, size_t ws_size,
                              hipStream_t stream) {
  const float* x  = (const float*)d_in[0];
  const float* w1 = (const float*)d_in[1];
  const float* b1 = (const float*)d_in[2];
  const float* wc = (const float*)d_in[3];
  const float* bc = (const float*)d_in[4];
  const float* wr = (const float*)d_in[5];
  const float* br = (const float*)d_in[6];
  const int* imw  = (const int*)d_in[7];
  const int* imh  = (const int*)d_in[8];
  float* out = (float*)d_out;
  char* ws = (char*)d_ws;
  float* hbuf = (float*)(ws + WS_H);
  f16* WH     = (f16*)(ws + WS_WT);
  f16* WL     = (f16*)(ws + WS_WT + 1179648);
  float* w54  = (float*)(ws + WS_W54);
  float* boxes = (float*)(ws + WS_BOXES);
  unsigned* keys = (unsigned*)(ws + WS_KEYS);
  float* sbox = (float*)(ws + WS_SBOX);
  int* sval   = (int*)(ws + WS_SVAL);
  unsigned long long* mask  = (unsigned long long*)(ws + WS_MASK);

  k_prep_all<<<2304, 256, 0, stream>>>(w1, wc, wr, WH, WL, w54, out + OUT_ANCH);
  k_conv3x3<<<2912, 256, 0, stream>>>(x, WH, WL, b1, hbuf);
  k_heads<<<313, 256, 0, stream>>>(hbuf, w54, bc, br, imw, imh,
                                   out + OUT_CLS, out + OUT_REG, boxes, keys);
  k_select<<<NB, 1024, 0, stream>>>(keys, boxes, sbox, sval);
  k_mask<<<dim3(NW64, 12, NB), 256, 0, stream>>>(sbox, mask);
  k_nms_final<<<NB, 256, 0, stream>>>(mask, sval, sbox, out + OUT_ROIS, out + OUT_RIND);
}